// Round 1
// baseline (491.570 us; speedup 1.0000x reference)
//
#include <hip/hip_runtime.h>
#include <math.h>

#define N_TOKENS 4096
#define D_MODEL  1024
#define N_EXPERT 8
#define D_HIDDEN 1024

typedef __bf16 bf16x8 __attribute__((ext_vector_type(8)));
typedef float  f32x4  __attribute__((ext_vector_type(4)));

#define GLOBAL_AS __attribute__((address_space(1)))
#define LDS_AS    __attribute__((address_space(3)))

static __device__ __forceinline__ void async_ld16(const void* g, void* l) {
    __builtin_amdgcn_global_load_lds((GLOBAL_AS void*)g, (LDS_AS void*)l, 16, 0, 0);
}

static __device__ __forceinline__ unsigned short f2bf(float f) {
    unsigned int u = __builtin_bit_cast(unsigned int, f);
    u += 0x7fffu + ((u >> 16) & 1u);      // round-to-nearest-even
    return (unsigned short)(u >> 16);
}
static __device__ __forceinline__ unsigned int pack2(float a, float b) {
    return (unsigned int)f2bf(a) | ((unsigned int)f2bf(b) << 16);
}

// ---------------------------------------------------------------------------
// Convert fp32 weights to bf16, TRANSPOSED to [N][K] (K-contiguous) so the
// GEMM can stage B with global_load_lds (wave-uniform-base contiguous rows).
// w1[e]: [D][H] -> w1b[e]: [H][D];  w2[e]: [H][D] -> w2b[e]: [D][H]
// ---------------------------------------------------------------------------
__global__ __launch_bounds__(256) void convert_transpose_kernel(
    const float* __restrict__ w1, const float* __restrict__ w2,
    unsigned short* __restrict__ w1b, unsigned short* __restrict__ w2b)
{
    int mat = blockIdx.z;   // 0..7: w1 experts, 8..15: w2 experts
    const float* src = (mat < 8) ? (w1 + (size_t)mat * 1048576)
                                 : (w2 + (size_t)(mat - 8) * 1048576);
    unsigned short* dst = (mat < 8) ? (w1b + (size_t)mat * 1048576)
                                    : (w2b + (size_t)(mat - 8) * 1048576);
    __shared__ float tile[64][65];
    int r0 = blockIdx.x * 64, c0 = blockIdx.y * 64;
    int tid = threadIdx.x;
    int lc = tid & 63, g = tid >> 6;          // g: 4 groups of 16 rows
    #pragma unroll
    for (int i = 0; i < 16; ++i) {
        int lr = g * 16 + i;
        tile[lr][lc] = src[(size_t)(r0 + lr) * 1024 + c0 + lc];
    }
    __syncthreads();
    #pragma unroll
    for (int i = 0; i < 16; ++i) {
        int a = g * 16 + i;                   // output row within tile = src col
        dst[(size_t)(c0 + a) * 1024 + r0 + lc] = f2bf(tile[lc][a]);
    }
}

// ---------------------------------------------------------------------------
// Gate: fp32-exact. One wave per token. Also initializes out = coeff @ b2.
// ---------------------------------------------------------------------------
__global__ __launch_bounds__(256) void gate_kernel(
    const float* __restrict__ inp, const float* __restrict__ gate_w,
    const float* __restrict__ gate_b, const float* __restrict__ b2,
    float* __restrict__ out, int* __restrict__ counts,
    int* __restrict__ lists, float* __restrict__ scores)
{
    int lane = threadIdx.x & 63, wave = threadIdx.x >> 6;
    int n = blockIdx.x * 4 + wave;
    const float* ip = inp + (size_t)n * D_MODEL;
    float acc[8] = {0.f,0.f,0.f,0.f,0.f,0.f,0.f,0.f};
    for (int d = lane; d < D_MODEL; d += 64) {
        float x = ip[d];
        float4 g0 = *(const float4*)(gate_w + d * 8);
        float4 g1 = *(const float4*)(gate_w + d * 8 + 4);
        acc[0] += x * g0.x; acc[1] += x * g0.y; acc[2] += x * g0.z; acc[3] += x * g0.w;
        acc[4] += x * g1.x; acc[5] += x * g1.y; acc[6] += x * g1.z; acc[7] += x * g1.w;
    }
    #pragma unroll
    for (int off = 32; off > 0; off >>= 1)
        #pragma unroll
        for (int e = 0; e < 8; ++e)
            acc[e] += __shfl_xor(acc[e], off, 64);
    #pragma unroll
    for (int e = 0; e < 8; ++e) acc[e] += gate_b[e];

    // top-2, strictly-greater => lowest index wins ties (matches lax.top_k)
    int e0 = 0; float v0 = acc[0];
    #pragma unroll
    for (int e = 1; e < 8; ++e) if (acc[e] > v0) { v0 = acc[e]; e0 = e; }
    int e1 = -1; float v1 = -1e30f;
    #pragma unroll
    for (int e = 0; e < 8; ++e) if (e != e0 && acc[e] > v1) { v1 = acc[e]; e1 = e; }
    float t  = expf(v1 - v0);
    float s0 = 1.0f / (1.0f + t);
    float s1 = t / (1.0f + t);

    if (lane == 0) {
        int p0 = atomicAdd(&counts[e0], 1);
        lists[e0 * N_TOKENS + p0] = n * 2;
        int p1 = atomicAdd(&counts[e1], 1);
        lists[e1 * N_TOKENS + p1] = n * 2 + 1;
        scores[n * 2]     = s0;
        scores[n * 2 + 1] = s1;
    }
    // out init = s0*b2[e0] + s1*b2[e1]
    const float* bA = b2 + (size_t)e0 * D_MODEL;
    const float* bB = b2 + (size_t)e1 * D_MODEL;
    float* op = out + (size_t)n * D_MODEL;
    for (int d = lane * 4; d < D_MODEL; d += 256) {
        float4 xa = *(const float4*)(bA + d);
        float4 xb = *(const float4*)(bB + d);
        float4 r;
        r.x = s0 * xa.x + s1 * xb.x; r.y = s0 * xa.y + s1 * xb.y;
        r.z = s0 * xa.z + s1 * xb.z; r.w = s0 * xa.w + s1 * xb.w;
        *(float4*)(op + d) = r;
    }
}

// ---------------------------------------------------------------------------
// Grouped GEMM1: H[entry] = gelu( inp[token] @ w1b[e]^T + b1[e] ), bf16 out.
// 128x128 tile, BK=32, mfma_f32_16x16x32_bf16, XOR-swizzled LDS chunks.
// ---------------------------------------------------------------------------
__global__ __launch_bounds__(256) void ffn1_kernel(
    const float* __restrict__ inp, const unsigned short* __restrict__ w1b,
    const float* __restrict__ b1, const int* __restrict__ counts,
    const int* __restrict__ lists, unsigned short* __restrict__ H)
{
    int e  = blockIdx.z;
    int Ne = counts[e];
    int m0 = blockIdx.x * 128;
    if (m0 >= Ne) return;
    int n0 = blockIdx.y * 128;

    __shared__ unsigned short As[128 * 32];
    __shared__ unsigned short Bs[128 * 32];
    __shared__ int rowid[128];

    int tid = threadIdx.x, lane = tid & 63, wave = tid >> 6;
    if (tid < 128) {
        int r = m0 + tid;
        rowid[tid] = lists[e * N_TOKENS + (r < Ne ? r : (Ne - 1))];
    }
    __syncthreads();

    // A staging: thread t loads 16 fp32 of row t>>1, half t&1; converts to bf16
    int arow = tid >> 1, ahalf = tid & 1;
    int sA    = (tid >> 2) & 3;                 // swizzle key for this row
    int slot0 = (2 * ahalf) ^ sA;
    const float* aptr = inp + (size_t)(rowid[arow] >> 1) * D_MODEL + ahalf * 16;
    unsigned short* aw0 = &As[arow * 32 + slot0 * 8];
    unsigned short* aw1 = &As[arow * 32 + (slot0 ^ 1) * 8];

    // B staging via global_load_lds: wave w -> Bs rows [w*32, w*32+32)
    int kc = (((lane & 3) ^ ((lane >> 3) & 3)) * 8);   // swizzled k-chunk (elems)
    const unsigned short* bexp = w1b + (size_t)e * D_MODEL * D_HIDDEN;
    const unsigned short* bptr =
        bexp + (size_t)(n0 + wave * 32 + (lane >> 2)) * D_MODEL + kc;
    unsigned short* bs0 = &Bs[(wave * 32) * 32];
    unsigned short* bs1 = &Bs[(wave * 32 + 16) * 32];

    f32x4 zero = {0.f, 0.f, 0.f, 0.f};
    f32x4 acc[4][4];
    #pragma unroll
    for (int i = 0; i < 4; ++i)
        #pragma unroll
        for (int j = 0; j < 4; ++j) acc[i][j] = zero;

    int wm = (wave & 1) * 64, wn = (wave >> 1) * 64;
    int lane15 = lane & 15, quad = lane >> 4;
    int fro = ((quad ^ ((lane15 >> 1) & 3)) * 8);      // swizzled frag offset

    for (int k0 = 0; k0 < D_MODEL; k0 += 32) {
        async_ld16(bptr + k0, bs0);
        async_ld16(bptr + (size_t)16 * D_MODEL + k0, bs1);
        float4 a0 = *(const float4*)(aptr + k0);
        float4 a1 = *(const float4*)(aptr + k0 + 4);
        float4 a2 = *(const float4*)(aptr + k0 + 8);
        float4 a3 = *(const float4*)(aptr + k0 + 12);
        uint4 p0, p1;
        p0.x = pack2(a0.x, a0.y); p0.y = pack2(a0.z, a0.w);
        p0.z = pack2(a1.x, a1.y); p0.w = pack2(a1.z, a1.w);
        p1.x = pack2(a2.x, a2.y); p1.y = pack2(a2.z, a2.w);
        p1.z = pack2(a3.x, a3.y); p1.w = pack2(a3.z, a3.w);
        *(uint4*)aw0 = p0;
        *(uint4*)aw1 = p1;
        __syncthreads();
        bf16x8 af[4], bf[4];
        #pragma unroll
        for (int t = 0; t < 4; ++t)
            af[t] = *(const bf16x8*)&As[(wm + t * 16 + lane15) * 32 + fro];
        #pragma unroll
        for (int t = 0; t < 4; ++t)
            bf[t] = *(const bf16x8*)&Bs[(wn + t * 16 + lane15) * 32 + fro];
        #pragma unroll
        for (int i = 0; i < 4; ++i)
            #pragma unroll
            for (int j = 0; j < 4; ++j)
                acc[i][j] = __builtin_amdgcn_mfma_f32_16x16x32_bf16(
                    af[i], bf[j], acc[i][j], 0, 0, 0);
        __syncthreads();
    }

    // epilogue: bias + exact-erf gelu -> bf16 H[entry][col]
    #pragma unroll
    for (int j = 0; j < 4; ++j) {
        int gcol = n0 + wn + j * 16 + lane15;
        float bv = b1[e * D_HIDDEN + gcol];
        #pragma unroll
        for (int i = 0; i < 4; ++i) {
            int browb = wm + i * 16 + quad * 4;
            #pragma unroll
            for (int r = 0; r < 4; ++r) {
                int row = browb + r;
                if (m0 + row < Ne) {
                    float x = acc[i][j][r] + bv;
                    float gv = 0.5f * x * (1.0f + erff(x * 0.70710678118654752f));
                    H[(size_t)rowid[row] * D_HIDDEN + gcol] = f2bf(gv);
                }
            }
        }
    }
}

// ---------------------------------------------------------------------------
// Grouped GEMM2: out[token] += score * ( H[entry] @ w2b[e]^T )
// ---------------------------------------------------------------------------
__global__ __launch_bounds__(256) void ffn2_kernel(
    const unsigned short* __restrict__ H, const unsigned short* __restrict__ w2b,
    const int* __restrict__ counts, const int* __restrict__ lists,
    const float* __restrict__ scores, float* __restrict__ out)
{
    int e  = blockIdx.z;
    int Ne = counts[e];
    int m0 = blockIdx.x * 128;
    if (m0 >= Ne) return;
    int n0 = blockIdx.y * 128;

    __shared__ unsigned short As[128 * 32];
    __shared__ unsigned short Bs[128 * 32];
    __shared__ int   rowid[128];
    __shared__ float rowsc[128];

    int tid = threadIdx.x, lane = tid & 63, wave = tid >> 6;
    if (tid < 128) {
        int r = m0 + tid;
        int entry = lists[e * N_TOKENS + (r < Ne ? r : (Ne - 1))];
        rowid[tid] = entry;
        rowsc[tid] = scores[entry];
    }
    __syncthreads();

    int kc = (((lane & 3) ^ ((lane >> 3) & 3)) * 8);
    const unsigned short* aptr0 =
        H + (size_t)rowid[wave * 32 + (lane >> 2)] * D_HIDDEN + kc;
    const unsigned short* aptr1 =
        H + (size_t)rowid[wave * 32 + 16 + (lane >> 2)] * D_HIDDEN + kc;
    unsigned short* as0 = &As[(wave * 32) * 32];
    unsigned short* as1 = &As[(wave * 32 + 16) * 32];

    const unsigned short* bexp = w2b + (size_t)e * D_HIDDEN * D_MODEL;
    const unsigned short* bptr =
        bexp + (size_t)(n0 + wave * 32 + (lane >> 2)) * D_HIDDEN + kc;
    unsigned short* bs0 = &Bs[(wave * 32) * 32];
    unsigned short* bs1 = &Bs[(wave * 32 + 16) * 32];

    f32x4 zero = {0.f, 0.f, 0.f, 0.f};
    f32x4 acc[4][4];
    #pragma unroll
    for (int i = 0; i < 4; ++i)
        #pragma unroll
        for (int j = 0; j < 4; ++j) acc[i][j] = zero;

    int wm = (wave & 1) * 64, wn = (wave >> 1) * 64;
    int lane15 = lane & 15, quad = lane >> 4;
    int fro = ((quad ^ ((lane15 >> 1) & 3)) * 8);

    for (int k0 = 0; k0 < D_HIDDEN; k0 += 32) {
        async_ld16(aptr0 + k0, as0);
        async_ld16(aptr1 + k0, as1);
        async_ld16(bptr + k0, bs0);
        async_ld16(bptr + (size_t)16 * D_HIDDEN + k0, bs1);
        __syncthreads();
        bf16x8 af[4], bf[4];
        #pragma unroll
        for (int t = 0; t < 4; ++t)
            af[t] = *(const bf16x8*)&As[(wm + t * 16 + lane15) * 32 + fro];
        #pragma unroll
        for (int t = 0; t < 4; ++t)
            bf[t] = *(const bf16x8*)&Bs[(wn + t * 16 + lane15) * 32 + fro];
        #pragma unroll
        for (int i = 0; i < 4; ++i)
            #pragma unroll
            for (int j = 0; j < 4; ++j)
                acc[i][j] = __builtin_amdgcn_mfma_f32_16x16x32_bf16(
                    af[i], bf[j], acc[i][j], 0, 0, 0);
        __syncthreads();
    }

    #pragma unroll
    for (int j = 0; j < 4; ++j) {
        int gcol = n0 + wn + j * 16 + lane15;
        #pragma unroll
        for (int i = 0; i < 4; ++i) {
            int browb = wm + i * 16 + quad * 4;
            #pragma unroll
            for (int r = 0; r < 4; ++r) {
                int row = browb + r;
                if (m0 + row < Ne) {
                    int entry = rowid[row];
                    atomicAdd(&out[(size_t)(entry >> 1) * D_MODEL + gcol],
                              rowsc[row] * acc[i][j][r]);
                }
            }
        }
    }
}

// ---------------------------------------------------------------------------
extern "C" void kernel_launch(void* const* d_in, const int* in_sizes, int n_in,
                              void* d_out, int out_size, void* d_ws, size_t ws_size,
                              hipStream_t stream) {
    const float* inp    = (const float*)d_in[0];
    const float* gate_w = (const float*)d_in[1];
    const float* gate_b = (const float*)d_in[2];
    const float* w1     = (const float*)d_in[3];
    const float* b1     = (const float*)d_in[4];
    const float* w2     = (const float*)d_in[5];
    const float* b2     = (const float*)d_in[6];
    float* out = (float*)d_out;

    char* ws = (char*)d_ws;
    unsigned short* w1b   = (unsigned short*)(ws);
    unsigned short* w2b   = (unsigned short*)(ws + 16777216);
    unsigned short* Hbuf  = (unsigned short*)(ws + 33554432);
    int*            lists = (int*)(ws + 50331648);
    float*          score = (float*)(ws + 50331648 + 131072);
    int*            cnts  = (int*)(ws + 50331648 + 131072 + 32768);

    hipMemsetAsync(cnts, 0, N_EXPERT * sizeof(int), stream);
    convert_transpose_kernel<<<dim3(16, 16, 16), 256, 0, stream>>>(w1, w2, w1b, w2b);
    gate_kernel<<<dim3(N_TOKENS / 4), 256, 0, stream>>>(
        inp, gate_w, gate_b, b2, out, cnts, lists, score);
    ffn1_kernel<<<dim3(32, 8, 8), 256, 0, stream>>>(inp, w1b, b1, cnts, lists, Hbuf);
    ffn2_kernel<<<dim3(32, 8, 8), 256, 0, stream>>>(Hbuf, w2b, cnts, lists, score, out);
}

// Round 3
// 335.708 us; speedup vs baseline: 1.4643x; 1.4643x over previous
//
#include <hip/hip_runtime.h>
#include <math.h>

#define N_TOKENS 4096
#define D_MODEL  1024
#define N_EXPERT 8
#define D_HIDDEN 1024
#define N_POS    8192   // N_TOKENS * TOP_K

typedef __bf16 bf16x8 __attribute__((ext_vector_type(8)));
typedef float  f32x4  __attribute__((ext_vector_type(4)));
typedef unsigned short u16x8 __attribute__((ext_vector_type(8)));

#define GLOBAL_AS __attribute__((address_space(1)))
#define LDS_AS    __attribute__((address_space(3)))

static __device__ __forceinline__ void async_ld16(const void* g, void* l) {
    __builtin_amdgcn_global_load_lds((GLOBAL_AS void*)g, (LDS_AS void*)l, 16, 0, 0);
}

static __device__ __forceinline__ unsigned short f2bf(float f) {
    unsigned int u = __builtin_bit_cast(unsigned int, f);
    u += 0x7fffu + ((u >> 16) & 1u);      // round-to-nearest-even
    return (unsigned short)(u >> 16);
}
static __device__ __forceinline__ unsigned int pack2(float a, float b) {
    return (unsigned int)f2bf(a) | ((unsigned int)f2bf(b) << 16);
}

// ---------------------------------------------------------------------------
// fp32 -> bf16 transposed weight convert. src [K][N] -> dst [N][K] k-contig.
// ---------------------------------------------------------------------------
__global__ __launch_bounds__(256) void convert_transpose_kernel(
    const float* __restrict__ w1, const float* __restrict__ w2,
    unsigned short* __restrict__ w1b, unsigned short* __restrict__ w2b)
{
    int mat = blockIdx.z;   // 0..7: w1 experts, 8..15: w2 experts
    const float* src = (mat < 8) ? (w1 + (size_t)mat * 1048576)
                                 : (w2 + (size_t)(mat - 8) * 1048576);
    unsigned short* dst = (mat < 8) ? (w1b + (size_t)mat * 1048576)
                                    : (w2b + (size_t)(mat - 8) * 1048576);
    __shared__ float tile[64][68];
    int r0 = blockIdx.x * 64, c0 = blockIdx.y * 64;
    int tid = threadIdx.x;
    #pragma unroll
    for (int i = 0; i < 4; ++i) {
        int r = (tid >> 4) + i * 16;
        float4 v = *(const float4*)(src + (size_t)(r0 + r) * 1024 + c0 + (tid & 15) * 4);
        *(float4*)&tile[r][(tid & 15) * 4] = v;
    }
    __syncthreads();
    #pragma unroll
    for (int i = 0; i < 2; ++i) {
        int dr = (tid & 31) + i * 32;      // dst row within tile = src col
        int dc = (tid >> 5) * 8;           // dst col base = src row
        u16x8 o;
        #pragma unroll
        for (int j = 0; j < 8; ++j) o[j] = f2bf(tile[dc + j][dr]);
        *(u16x8*)(dst + (size_t)(c0 + dr) * 1024 + r0 + dc) = o;
    }
}

// ---------------------------------------------------------------------------
// Gate: fp32-exact top-2 + softmax. One wave per token.
// ---------------------------------------------------------------------------
__global__ __launch_bounds__(256) void gate_kernel(
    const float* __restrict__ inp, const float* __restrict__ gate_w,
    const float* __restrict__ gate_b, int* __restrict__ cnts,
    int* __restrict__ emeta, float* __restrict__ stok)
{
    int lane = threadIdx.x & 63, wave = threadIdx.x >> 6;
    int n = blockIdx.x * 4 + wave;
    const float* ip = inp + (size_t)n * D_MODEL;
    float acc[8] = {0.f,0.f,0.f,0.f,0.f,0.f,0.f,0.f};
    for (int d = lane; d < D_MODEL; d += 64) {
        float x = ip[d];
        float4 g0 = *(const float4*)(gate_w + d * 8);
        float4 g1 = *(const float4*)(gate_w + d * 8 + 4);
        acc[0] += x * g0.x; acc[1] += x * g0.y; acc[2] += x * g0.z; acc[3] += x * g0.w;
        acc[4] += x * g1.x; acc[5] += x * g1.y; acc[6] += x * g1.z; acc[7] += x * g1.w;
    }
    #pragma unroll
    for (int off = 32; off > 0; off >>= 1)
        #pragma unroll
        for (int e = 0; e < 8; ++e)
            acc[e] += __shfl_xor(acc[e], off, 64);
    #pragma unroll
    for (int e = 0; e < 8; ++e) acc[e] += gate_b[e];

    // top-2, strictly-greater => lowest index wins ties (matches lax.top_k)
    int e0 = 0; float v0 = acc[0];
    #pragma unroll
    for (int e = 1; e < 8; ++e) if (acc[e] > v0) { v0 = acc[e]; e0 = e; }
    int e1 = -1; float v1 = -1e30f;
    #pragma unroll
    for (int e = 0; e < 8; ++e) if (e != e0 && acc[e] > v1) { v1 = acc[e]; e1 = e; }
    float t  = expf(v1 - v0);
    float s0 = 1.0f / (1.0f + t);
    float s1 = t / (1.0f + t);

    if (lane == 0) {
        int p0 = atomicAdd(&cnts[e0], 1);
        int p1 = atomicAdd(&cnts[e1], 1);
        emeta[n] = e0 | (e1 << 4) | (p0 << 8) | (p1 << 20);
        stok[2 * n]     = s0;
        stok[2 * n + 1] = s1;
    }
}

// ---------------------------------------------------------------------------
// Gather: expert-sorted bf16 activation matrix Ag[N_POS][D_MODEL] (in d_out)
// + position->token / position->score maps.
// ---------------------------------------------------------------------------
__global__ __launch_bounds__(256) void gather_kernel(
    const float* __restrict__ inp, const int* __restrict__ cnts,
    const int* __restrict__ emeta, const float* __restrict__ stok,
    unsigned short* __restrict__ Ag, int* __restrict__ pos2tok,
    float* __restrict__ pos2score)
{
    int lane = threadIdx.x & 63, wave = threadIdx.x >> 6;
    int n = blockIdx.x * 4 + wave;
    unsigned int em = (unsigned int)emeta[n];
    int e0 = em & 15, e1 = (em >> 4) & 15;
    int p0 = (em >> 8) & 4095, p1 = (int)(em >> 20);
    int off0 = 0, off1 = 0;
    #pragma unroll
    for (int e = 0; e < 8; ++e) {
        int c = cnts[e];
        off0 += (e < e0) ? c : 0;
        off1 += (e < e1) ? c : 0;
    }
    int pos0 = off0 + p0, pos1 = off1 + p1;
    if (lane == 0) {
        pos2tok[pos0] = n;          pos2tok[pos1] = n;
        pos2score[pos0] = stok[2*n]; pos2score[pos1] = stok[2*n+1];
    }
    const float* ip = inp + (size_t)n * D_MODEL;
    unsigned short* r0 = Ag + (size_t)pos0 * D_MODEL;
    unsigned short* r1 = Ag + (size_t)pos1 * D_MODEL;
    for (int d = lane * 4; d < D_MODEL; d += 256) {
        float4 v = *(const float4*)(ip + d);
        uint2 u; u.x = pack2(v.x, v.y); u.y = pack2(v.z, v.w);
        *(uint2*)(r0 + d) = u;
        *(uint2*)(r1 + d) = u;
    }
}

// ---------------------------------------------------------------------------
// out = coeff @ b2  (runs AFTER ffn1 because Ag aliases d_out)
// ---------------------------------------------------------------------------
__global__ __launch_bounds__(256) void out_init_kernel(
    const int* __restrict__ emeta, const float* __restrict__ stok,
    const float* __restrict__ b2, float* __restrict__ out)
{
    int lane = threadIdx.x & 63, wave = threadIdx.x >> 6;
    int n = blockIdx.x * 4 + wave;
    unsigned int em = (unsigned int)emeta[n];
    int e0 = em & 15, e1 = (em >> 4) & 15;
    float s0 = stok[2 * n], s1 = stok[2 * n + 1];
    const float* bA = b2 + (size_t)e0 * D_MODEL;
    const float* bB = b2 + (size_t)e1 * D_MODEL;
    float* op = out + (size_t)n * D_MODEL;
    for (int d = lane * 4; d < D_MODEL; d += 256) {
        float4 xa = *(const float4*)(bA + d);
        float4 xb = *(const float4*)(bB + d);
        float4 r;
        r.x = s0 * xa.x + s1 * xb.x; r.y = s0 * xa.y + s1 * xb.y;
        r.z = s0 * xa.z + s1 * xb.z; r.w = s0 * xa.w + s1 * xb.w;
        *(float4*)(op + d) = r;
    }
}

// ---------------------------------------------------------------------------
// Grouped GEMM1: Hg[pos] = gelu( Ag[pos] @ w1b[e]^T + b1[e] )
// 128x128 tile, BK=64, all-async staging.
// A-source rows clamped PER-LANE (global_load_lds takes per-lane global
// addresses; LDS base must be wave-uniform; swizzle key depends only on the
// LDS row, so per-lane source clamping is safe). Base-clamping here was the
// R2 bug: it corrupted up to 15 valid tail rows of the last expert.
// ---------------------------------------------------------------------------
__global__ __launch_bounds__(256, 2) void ffn1_kernel(
    const unsigned short* __restrict__ Ag, const unsigned short* __restrict__ w1b,
    const float* __restrict__ b1, const int* __restrict__ cnts,
    unsigned short* __restrict__ Hg)
{
    int bid = blockIdx.x;
    int e = bid & 7, nt = (bid >> 3) & 7, mt = bid >> 6;
    int off = 0, Ne = 0;
    #pragma unroll
    for (int i = 0; i < 8; ++i) {
        int c = cnts[i];
        off += (i < e) ? c : 0;
        Ne = (i == e) ? c : Ne;
    }
    int m0 = mt * 128;
    if (m0 >= Ne) return;
    int n0 = nt * 128;

    __shared__ unsigned short As[2 * 128 * 32];   // [half][row][32], chunk-swizzled
    __shared__ unsigned short Bs[2 * 128 * 32];

    int tid = threadIdx.x, lane = tid & 63, wave = tid >> 6;
    int lrow = lane >> 2, lchunk = lane & 3;
    int csw8 = (lchunk ^ ((lrow >> 1) & 3)) * 8;

    int ga0 = off + m0 + wave * 32 + lrow;        // per-lane global source row
    int ga1 = ga0 + 16;
    if (ga0 >= N_POS) ga0 = N_POS - 1;            // rows >= segment end are
    if (ga1 >= N_POS) ga1 = N_POS - 1;            // masked in the epilogue
    const unsigned short* aS0 = Ag + (size_t)ga0 * D_MODEL + csw8;
    const unsigned short* aS1 = Ag + (size_t)ga1 * D_MODEL + csw8;
    const unsigned short* bS0 = w1b + (size_t)e * D_MODEL * D_HIDDEN
                              + (size_t)(n0 + wave * 32 + lrow) * D_MODEL + csw8;
    const unsigned short* bS1 = bS0 + (size_t)16 * D_MODEL;
    unsigned short* aD0 = &As[(wave * 32) * 32];
    unsigned short* aD1 = &As[(wave * 32 + 16) * 32];
    unsigned short* bD0 = &Bs[(wave * 32) * 32];
    unsigned short* bD1 = &Bs[(wave * 32 + 16) * 32];

    f32x4 acc[4][4] = {};
    int wm = (wave & 1) * 64, wn = (wave >> 1) * 64;
    int lane15 = lane & 15, quad = lane >> 4;
    int fro = (quad ^ ((lane15 >> 1) & 3)) * 8;

    for (int k0 = 0; k0 < D_MODEL; k0 += 64) {
        #pragma unroll
        for (int h = 0; h < 2; ++h) {
            int ko = k0 + h * 32;
            async_ld16(aS0 + ko, aD0 + h * 4096);
            async_ld16(aS1 + ko, aD1 + h * 4096);
            async_ld16(bS0 + ko, bD0 + h * 4096);
            async_ld16(bS1 + ko, bD1 + h * 4096);
        }
        __syncthreads();
        bf16x8 af[2][4], bf[2][4];
        #pragma unroll
        for (int h = 0; h < 2; ++h)
            #pragma unroll
            for (int t = 0; t < 4; ++t) {
                af[h][t] = *(const bf16x8*)&As[h * 4096 + (wm + t * 16 + lane15) * 32 + fro];
                bf[h][t] = *(const bf16x8*)&Bs[h * 4096 + (wn + t * 16 + lane15) * 32 + fro];
            }
        #pragma unroll
        for (int h = 0; h < 2; ++h)
            #pragma unroll
            for (int i = 0; i < 4; ++i)
                #pragma unroll
                for (int j = 0; j < 4; ++j)
                    acc[i][j] = __builtin_amdgcn_mfma_f32_16x16x32_bf16(
                        af[h][i], bf[h][j], acc[i][j], 0, 0, 0);
        __syncthreads();
    }

    const float* bexp = b1 + (size_t)e * D_HIDDEN;
    #pragma unroll
    for (int j = 0; j < 4; ++j) {
        int gcol = n0 + wn + j * 16 + lane15;
        float bv = bexp[gcol];
        #pragma unroll
        for (int i = 0; i < 4; ++i) {
            int rowb = wm + i * 16 + quad * 4;
            #pragma unroll
            for (int r = 0; r < 4; ++r) {
                int row = rowb + r;
                if (m0 + row < Ne) {
                    float x = acc[i][j][r] + bv;
                    float gv = 0.5f * x * (1.0f + erff(x * 0.70710678118654752f));
                    Hg[(size_t)(off + m0 + row) * D_HIDDEN + gcol] = f2bf(gv);
                }
            }
        }
    }
}

// ---------------------------------------------------------------------------
// Grouped GEMM2: out[tok] += score[pos] * ( Hg[pos] @ w2b[e]^T )
// ---------------------------------------------------------------------------
__global__ __launch_bounds__(256, 2) void ffn2_kernel(
    const unsigned short* __restrict__ Hg, const unsigned short* __restrict__ w2b,
    const int* __restrict__ cnts, const int* __restrict__ pos2tok,
    const float* __restrict__ pos2score, float* __restrict__ out)
{
    int bid = blockIdx.x;
    int e = bid & 7, nt = (bid >> 3) & 7, mt = bid >> 6;
    int off = 0, Ne = 0;
    #pragma unroll
    for (int i = 0; i < 8; ++i) {
        int c = cnts[i];
        off += (i < e) ? c : 0;
        Ne = (i == e) ? c : Ne;
    }
    int m0 = mt * 128;
    if (m0 >= Ne) return;
    int n0 = nt * 128;

    __shared__ unsigned short As[2 * 128 * 32];
    __shared__ unsigned short Bs[2 * 128 * 32];
    __shared__ int   ptok[128];
    __shared__ float psc[128];

    int tid = threadIdx.x, lane = tid & 63, wave = tid >> 6;
    int lrow = lane >> 2, lchunk = lane & 3;
    int csw8 = (lchunk ^ ((lrow >> 1) & 3)) * 8;

    int ga0 = off + m0 + wave * 32 + lrow;        // per-lane clamp (see ffn1)
    int ga1 = ga0 + 16;
    if (ga0 >= N_POS) ga0 = N_POS - 1;
    if (ga1 >= N_POS) ga1 = N_POS - 1;
    const unsigned short* aS0 = Hg + (size_t)ga0 * D_HIDDEN + csw8;
    const unsigned short* aS1 = Hg + (size_t)ga1 * D_HIDDEN + csw8;
    const unsigned short* bS0 = w2b + (size_t)e * D_HIDDEN * D_MODEL
                              + (size_t)(n0 + wave * 32 + lrow) * D_HIDDEN + csw8;
    const unsigned short* bS1 = bS0 + (size_t)16 * D_HIDDEN;
    unsigned short* aD0 = &As[(wave * 32) * 32];
    unsigned short* aD1 = &As[(wave * 32 + 16) * 32];
    unsigned short* bD0 = &Bs[(wave * 32) * 32];
    unsigned short* bD1 = &Bs[(wave * 32 + 16) * 32];

    f32x4 acc[4][4] = {};
    int wm = (wave & 1) * 64, wn = (wave >> 1) * 64;
    int lane15 = lane & 15, quad = lane >> 4;
    int fro = (quad ^ ((lane15 >> 1) & 3)) * 8;

    for (int k0 = 0; k0 < D_HIDDEN; k0 += 64) {
        #pragma unroll
        for (int h = 0; h < 2; ++h) {
            int ko = k0 + h * 32;
            async_ld16(aS0 + ko, aD0 + h * 4096);
            async_ld16(aS1 + ko, aD1 + h * 4096);
            async_ld16(bS0 + ko, bD0 + h * 4096);
            async_ld16(bS1 + ko, bD1 + h * 4096);
        }
        __syncthreads();
        bf16x8 af[2][4], bf[2][4];
        #pragma unroll
        for (int h = 0; h < 2; ++h)
            #pragma unroll
            for (int t = 0; t < 4; ++t) {
                af[h][t] = *(const bf16x8*)&As[h * 4096 + (wm + t * 16 + lane15) * 32 + fro];
                bf[h][t] = *(const bf16x8*)&Bs[h * 4096 + (wn + t * 16 + lane15) * 32 + fro];
            }
        #pragma unroll
        for (int h = 0; h < 2; ++h)
            #pragma unroll
            for (int i = 0; i < 4; ++i)
                #pragma unroll
                for (int j = 0; j < 4; ++j)
                    acc[i][j] = __builtin_amdgcn_mfma_f32_16x16x32_bf16(
                        af[h][i], bf[h][j], acc[i][j], 0, 0, 0);
        __syncthreads();
    }

    if (tid < 128) {
        int pos = off + m0 + tid;
        if (pos > N_POS - 1) pos = N_POS - 1;
        ptok[tid] = pos2tok[pos];
        psc[tid]  = pos2score[pos];
    }
    __syncthreads();

    #pragma unroll
    for (int j = 0; j < 4; ++j) {
        int gcol = n0 + wn + j * 16 + lane15;
        #pragma unroll
        for (int i = 0; i < 4; ++i) {
            int rowb = wm + i * 16 + quad * 4;
            #pragma unroll
            for (int r = 0; r < 4; ++r) {
                int row = rowb + r;
                if (m0 + row < Ne) {
                    atomicAdd(&out[(size_t)ptok[row] * D_MODEL + gcol],
                              psc[row] * acc[i][j][r]);
                }
            }
        }
    }
}

// ---------------------------------------------------------------------------
extern "C" void kernel_launch(void* const* d_in, const int* in_sizes, int n_in,
                              void* d_out, int out_size, void* d_ws, size_t ws_size,
                              hipStream_t stream) {
    const float* inp    = (const float*)d_in[0];
    const float* gate_w = (const float*)d_in[1];
    const float* gate_b = (const float*)d_in[2];
    const float* w1     = (const float*)d_in[3];
    const float* b1     = (const float*)d_in[4];
    const float* w2     = (const float*)d_in[5];
    const float* b2     = (const float*)d_in[6];
    float* out = (float*)d_out;

    char* ws = (char*)d_ws;
    unsigned short* w1b = (unsigned short*)(ws);                 // 16 MB
    unsigned short* w2b = (unsigned short*)(ws + 16777216);      // 16 MB
    unsigned short* Hg  = (unsigned short*)(ws + 33554432);      // 16 MB
    int*   cnts    = (int*)  (ws + 50331648);                    // 32 B (pad 128)
    int*   emeta   = (int*)  (ws + 50331776);                    // 16 KB
    float* stok    = (float*)(ws + 50348160);                    // 32 KB
    int*   pos2tok = (int*)  (ws + 50380928);                    // 32 KB
    float* pos2sc  = (float*)(ws + 50413696);                    // 32 KB

    // Ag (expert-sorted bf16 activations) lives in d_out: exactly 16 MB.
    unsigned short* Ag = (unsigned short*)d_out;

    hipMemsetAsync(cnts, 0, N_EXPERT * sizeof(int), stream);
    convert_transpose_kernel<<<dim3(16, 16, 16), 256, 0, stream>>>(w1, w2, w1b, w2b);
    gate_kernel<<<dim3(N_TOKENS / 4), 256, 0, stream>>>(
        inp, gate_w, gate_b, cnts, emeta, stok);
    gather_kernel<<<dim3(N_TOKENS / 4), 256, 0, stream>>>(
        inp, cnts, emeta, stok, Ag, pos2tok, pos2sc);
    ffn1_kernel<<<dim3(2048), 256, 0, stream>>>(Ag, w1b, b1, cnts, Hg);
    out_init_kernel<<<dim3(N_TOKENS / 4), 256, 0, stream>>>(emeta, stok, b2, out);
    ffn2_kernel<<<dim3(2048), 256, 0, stream>>>(Hg, w2b, cnts, pos2tok, pos2sc, out);
}

// Round 4
// 252.146 us; speedup vs baseline: 1.9495x; 1.3314x over previous
//
#include <hip/hip_runtime.h>
#include <math.h>

#define N_TOKENS 4096
#define D_MODEL  1024
#define N_EXPERT 8
#define D_HIDDEN 1024
#define N_POS    8192   // N_TOKENS * TOP_K

typedef __bf16 bf16x8 __attribute__((ext_vector_type(8)));
typedef float  f32x4  __attribute__((ext_vector_type(4)));
typedef unsigned short u16x8 __attribute__((ext_vector_type(8)));

#define GLOBAL_AS __attribute__((address_space(1)))
#define LDS_AS    __attribute__((address_space(3)))

static __device__ __forceinline__ void async_ld16(const void* g, void* l) {
    __builtin_amdgcn_global_load_lds((GLOBAL_AS void*)g, (LDS_AS void*)l, 16, 0, 0);
}

static __device__ __forceinline__ unsigned short f2bf(float f) {
    unsigned int u = __builtin_bit_cast(unsigned int, f);
    u += 0x7fffu + ((u >> 16) & 1u);      // round-to-nearest-even
    return (unsigned short)(u >> 16);
}
static __device__ __forceinline__ unsigned int pack2(float a, float b) {
    return (unsigned int)f2bf(a) | ((unsigned int)f2bf(b) << 16);
}

// ---------------------------------------------------------------------------
// fp32 -> bf16 transposed weight convert. src [K][N] -> dst [N][K] k-contig.
// ---------------------------------------------------------------------------
__global__ __launch_bounds__(256) void convert_transpose_kernel(
    const float* __restrict__ w1, const float* __restrict__ w2,
    unsigned short* __restrict__ w1b, unsigned short* __restrict__ w2b)
{
    int mat = blockIdx.z;   // 0..7: w1 experts, 8..15: w2 experts
    const float* src = (mat < 8) ? (w1 + (size_t)mat * 1048576)
                                 : (w2 + (size_t)(mat - 8) * 1048576);
    unsigned short* dst = (mat < 8) ? (w1b + (size_t)mat * 1048576)
                                    : (w2b + (size_t)(mat - 8) * 1048576);
    __shared__ float tile[64][68];
    int r0 = blockIdx.x * 64, c0 = blockIdx.y * 64;
    int tid = threadIdx.x;
    #pragma unroll
    for (int i = 0; i < 4; ++i) {
        int r = (tid >> 4) + i * 16;
        float4 v = *(const float4*)(src + (size_t)(r0 + r) * 1024 + c0 + (tid & 15) * 4);
        *(float4*)&tile[r][(tid & 15) * 4] = v;
    }
    __syncthreads();
    #pragma unroll
    for (int i = 0; i < 2; ++i) {
        int dr = (tid & 31) + i * 32;      // dst row within tile = src col
        int dc = (tid >> 5) * 8;           // dst col base = src row
        u16x8 o;
        #pragma unroll
        for (int j = 0; j < 8; ++j) o[j] = f2bf(tile[dc + j][dr]);
        *(u16x8*)(dst + (size_t)(c0 + dr) * 1024 + r0 + dc) = o;
    }
}

// ---------------------------------------------------------------------------
// Gate: fp32-exact top-2 + softmax. Wave per token-quad; BLOCK-AGGREGATED
// ranking (R3's 8192 same-line global atomics serialized at ~13 ns/op =
// 107 us; now: LDS atomics for local rank + 8 global atomics per block).
// ---------------------------------------------------------------------------
__global__ __launch_bounds__(256) void gate_kernel(
    const float* __restrict__ inp, const float* __restrict__ gate_w,
    const float* __restrict__ gate_b, int* __restrict__ cnts,
    int* __restrict__ emeta, float* __restrict__ stok)
{
    __shared__ int bcnt[8], base[8];
    __shared__ int tinfo[16];   // e0 | e1<<4 | r0<<8 | r1<<20 (block-local)
    int tid = threadIdx.x, lane = tid & 63, wave = tid >> 6;
    if (tid < 8) bcnt[tid] = 0;
    __syncthreads();

    for (int t = 0; t < 4; ++t) {
        int ti = wave * 4 + t;
        int n  = blockIdx.x * 16 + ti;
        const float* ip = inp + (size_t)n * D_MODEL;
        float acc[8] = {0.f,0.f,0.f,0.f,0.f,0.f,0.f,0.f};
        for (int d0 = lane * 4; d0 < D_MODEL; d0 += 256) {
            float4 x = *(const float4*)(ip + d0);
            #pragma unroll
            for (int j = 0; j < 4; ++j) {
                float xv = (j == 0) ? x.x : (j == 1) ? x.y : (j == 2) ? x.z : x.w;
                float4 g0 = *(const float4*)(gate_w + (d0 + j) * 8);
                float4 g1 = *(const float4*)(gate_w + (d0 + j) * 8 + 4);
                acc[0] += xv * g0.x; acc[1] += xv * g0.y;
                acc[2] += xv * g0.z; acc[3] += xv * g0.w;
                acc[4] += xv * g1.x; acc[5] += xv * g1.y;
                acc[6] += xv * g1.z; acc[7] += xv * g1.w;
            }
        }
        #pragma unroll
        for (int off = 32; off > 0; off >>= 1)
            #pragma unroll
            for (int e = 0; e < 8; ++e)
                acc[e] += __shfl_xor(acc[e], off, 64);
        #pragma unroll
        for (int e = 0; e < 8; ++e) acc[e] += gate_b[e];

        // top-2; strictly-greater => lowest index wins ties (lax.top_k)
        int e0 = 0; float v0 = acc[0];
        #pragma unroll
        for (int e = 1; e < 8; ++e) if (acc[e] > v0) { v0 = acc[e]; e0 = e; }
        int e1 = -1; float v1 = -1e30f;
        #pragma unroll
        for (int e = 0; e < 8; ++e) if (e != e0 && acc[e] > v1) { v1 = acc[e]; e1 = e; }
        float tv = expf(v1 - v0);
        float s0 = 1.0f / (1.0f + tv);
        float s1 = tv / (1.0f + tv);

        if (lane == 0) {
            int r0 = atomicAdd(&bcnt[e0], 1);   // LDS atomic: block-local rank
            int r1 = atomicAdd(&bcnt[e1], 1);
            tinfo[ti] = e0 | (e1 << 4) | (r0 << 8) | (r1 << 20);
            stok[2 * n]     = s0;
            stok[2 * n + 1] = s1;
        }
    }
    __syncthreads();
    if (tid < 8) base[tid] = atomicAdd(&cnts[tid], bcnt[tid]);  // 8 globals/block
    __syncthreads();
    if (tid < 16) {
        int n = blockIdx.x * 16 + tid;
        unsigned int inf = (unsigned int)tinfo[tid];
        int e0 = inf & 15, e1 = (inf >> 4) & 15;
        int p0 = base[e0] + ((inf >> 8) & 4095);
        int p1 = base[e1] + (int)(inf >> 20);
        emeta[n] = e0 | (e1 << 4) | (p0 << 8) | (p1 << 20);
    }
}

// ---------------------------------------------------------------------------
// Gather: expert-sorted bf16 activation matrix Ag[N_POS][D_MODEL] (in d_out)
// + position->token / position->score maps.
// ---------------------------------------------------------------------------
__global__ __launch_bounds__(256) void gather_kernel(
    const float* __restrict__ inp, const int* __restrict__ cnts,
    const int* __restrict__ emeta, const float* __restrict__ stok,
    unsigned short* __restrict__ Ag, int* __restrict__ pos2tok,
    float* __restrict__ pos2score)
{
    int lane = threadIdx.x & 63, wave = threadIdx.x >> 6;
    int n = blockIdx.x * 4 + wave;
    unsigned int em = (unsigned int)emeta[n];
    int e0 = em & 15, e1 = (em >> 4) & 15;
    int p0 = (em >> 8) & 4095, p1 = (int)(em >> 20);
    int off0 = 0, off1 = 0;
    #pragma unroll
    for (int e = 0; e < 8; ++e) {
        int c = cnts[e];
        off0 += (e < e0) ? c : 0;
        off1 += (e < e1) ? c : 0;
    }
    int pos0 = off0 + p0, pos1 = off1 + p1;
    if (lane == 0) {
        pos2tok[pos0] = n;          pos2tok[pos1] = n;
        pos2score[pos0] = stok[2*n]; pos2score[pos1] = stok[2*n+1];
    }
    const float* ip = inp + (size_t)n * D_MODEL;
    unsigned short* r0 = Ag + (size_t)pos0 * D_MODEL;
    unsigned short* r1 = Ag + (size_t)pos1 * D_MODEL;
    for (int d = lane * 4; d < D_MODEL; d += 256) {
        float4 v = *(const float4*)(ip + d);
        uint2 u; u.x = pack2(v.x, v.y); u.y = pack2(v.z, v.w);
        *(uint2*)(r0 + d) = u;
        *(uint2*)(r1 + d) = u;
    }
}

// ---------------------------------------------------------------------------
// out = coeff @ b2  (runs AFTER ffn1 because Ag aliases d_out)
// ---------------------------------------------------------------------------
__global__ __launch_bounds__(256) void out_init_kernel(
    const int* __restrict__ emeta, const float* __restrict__ stok,
    const float* __restrict__ b2, float* __restrict__ out)
{
    int lane = threadIdx.x & 63, wave = threadIdx.x >> 6;
    int n = blockIdx.x * 4 + wave;
    unsigned int em = (unsigned int)emeta[n];
    int e0 = em & 15, e1 = (em >> 4) & 15;
    float s0 = stok[2 * n], s1 = stok[2 * n + 1];
    const float* bA = b2 + (size_t)e0 * D_MODEL;
    const float* bB = b2 + (size_t)e1 * D_MODEL;
    float* op = out + (size_t)n * D_MODEL;
    for (int d = lane * 4; d < D_MODEL; d += 256) {
        float4 xa = *(const float4*)(bA + d);
        float4 xb = *(const float4*)(bB + d);
        float4 r;
        r.x = s0 * xa.x + s1 * xb.x; r.y = s0 * xa.y + s1 * xb.y;
        r.z = s0 * xa.z + s1 * xb.z; r.w = s0 * xa.w + s1 * xb.w;
        *(float4*)(op + d) = r;
    }
}

// ---------------------------------------------------------------------------
// Grouped GEMM1: Hg[pos] = gelu( Ag[pos] @ w1b[e]^T + b1[e] )
// 128x128 tile, BK=64, all-async staging, per-lane source-row clamp.
// ---------------------------------------------------------------------------
__global__ __launch_bounds__(256, 2) void ffn1_kernel(
    const unsigned short* __restrict__ Ag, const unsigned short* __restrict__ w1b,
    const float* __restrict__ b1, const int* __restrict__ cnts,
    unsigned short* __restrict__ Hg)
{
    int bid = blockIdx.x;
    int e = bid & 7, nt = (bid >> 3) & 7, mt = bid >> 6;
    int off = 0, Ne = 0;
    #pragma unroll
    for (int i = 0; i < 8; ++i) {
        int c = cnts[i];
        off += (i < e) ? c : 0;
        Ne = (i == e) ? c : Ne;
    }
    int m0 = mt * 128;
    if (m0 >= Ne) return;
    int n0 = nt * 128;

    __shared__ unsigned short As[2 * 128 * 32];   // [half][row][32], chunk-swizzled
    __shared__ unsigned short Bs[2 * 128 * 32];

    int tid = threadIdx.x, lane = tid & 63, wave = tid >> 6;
    int lrow = lane >> 2, lchunk = lane & 3;
    int csw8 = (lchunk ^ ((lrow >> 1) & 3)) * 8;

    int ga0 = off + m0 + wave * 32 + lrow;        // per-lane global source row
    int ga1 = ga0 + 16;
    if (ga0 >= N_POS) ga0 = N_POS - 1;            // rows >= segment end are
    if (ga1 >= N_POS) ga1 = N_POS - 1;            // masked in the epilogue
    const unsigned short* aS0 = Ag + (size_t)ga0 * D_MODEL + csw8;
    const unsigned short* aS1 = Ag + (size_t)ga1 * D_MODEL + csw8;
    const unsigned short* bS0 = w1b + (size_t)e * D_MODEL * D_HIDDEN
                              + (size_t)(n0 + wave * 32 + lrow) * D_MODEL + csw8;
    const unsigned short* bS1 = bS0 + (size_t)16 * D_MODEL;
    unsigned short* aD0 = &As[(wave * 32) * 32];
    unsigned short* aD1 = &As[(wave * 32 + 16) * 32];
    unsigned short* bD0 = &Bs[(wave * 32) * 32];
    unsigned short* bD1 = &Bs[(wave * 32 + 16) * 32];

    f32x4 acc[4][4] = {};
    int wm = (wave & 1) * 64, wn = (wave >> 1) * 64;
    int lane15 = lane & 15, quad = lane >> 4;
    int fro = (quad ^ ((lane15 >> 1) & 3)) * 8;

    for (int k0 = 0; k0 < D_MODEL; k0 += 64) {
        #pragma unroll
        for (int h = 0; h < 2; ++h) {
            int ko = k0 + h * 32;
            async_ld16(aS0 + ko, aD0 + h * 4096);
            async_ld16(aS1 + ko, aD1 + h * 4096);
            async_ld16(bS0 + ko, bD0 + h * 4096);
            async_ld16(bS1 + ko, bD1 + h * 4096);
        }
        __syncthreads();
        bf16x8 af[2][4], bf[2][4];
        #pragma unroll
        for (int h = 0; h < 2; ++h)
            #pragma unroll
            for (int t = 0; t < 4; ++t) {
                af[h][t] = *(const bf16x8*)&As[h * 4096 + (wm + t * 16 + lane15) * 32 + fro];
                bf[h][t] = *(const bf16x8*)&Bs[h * 4096 + (wn + t * 16 + lane15) * 32 + fro];
            }
        #pragma unroll
        for (int h = 0; h < 2; ++h)
            #pragma unroll
            for (int i = 0; i < 4; ++i)
                #pragma unroll
                for (int j = 0; j < 4; ++j)
                    acc[i][j] = __builtin_amdgcn_mfma_f32_16x16x32_bf16(
                        af[h][i], bf[h][j], acc[i][j], 0, 0, 0);
        __syncthreads();
    }

    const float* bexp = b1 + (size_t)e * D_HIDDEN;
    #pragma unroll
    for (int j = 0; j < 4; ++j) {
        int gcol = n0 + wn + j * 16 + lane15;
        float bv = bexp[gcol];
        #pragma unroll
        for (int i = 0; i < 4; ++i) {
            int rowb = wm + i * 16 + quad * 4;
            #pragma unroll
            for (int r = 0; r < 4; ++r) {
                int row = rowb + r;
                if (m0 + row < Ne) {
                    float x = acc[i][j][r] + bv;
                    float gv = 0.5f * x * (1.0f + erff(x * 0.70710678118654752f));
                    Hg[(size_t)(off + m0 + row) * D_HIDDEN + gcol] = f2bf(gv);
                }
            }
        }
    }
}

// ---------------------------------------------------------------------------
// Grouped GEMM2: out[tok] += score[pos] * ( Hg[pos] @ w2b[e]^T )
// ---------------------------------------------------------------------------
__global__ __launch_bounds__(256, 2) void ffn2_kernel(
    const unsigned short* __restrict__ Hg, const unsigned short* __restrict__ w2b,
    const int* __restrict__ cnts, const int* __restrict__ pos2tok,
    const float* __restrict__ pos2score, float* __restrict__ out)
{
    int bid = blockIdx.x;
    int e = bid & 7, nt = (bid >> 3) & 7, mt = bid >> 6;
    int off = 0, Ne = 0;
    #pragma unroll
    for (int i = 0; i < 8; ++i) {
        int c = cnts[i];
        off += (i < e) ? c : 0;
        Ne = (i == e) ? c : Ne;
    }
    int m0 = mt * 128;
    if (m0 >= Ne) return;
    int n0 = nt * 128;

    __shared__ unsigned short As[2 * 128 * 32];
    __shared__ unsigned short Bs[2 * 128 * 32];
    __shared__ int   ptok[128];
    __shared__ float psc[128];

    int tid = threadIdx.x, lane = tid & 63, wave = tid >> 6;
    int lrow = lane >> 2, lchunk = lane & 3;
    int csw8 = (lchunk ^ ((lrow >> 1) & 3)) * 8;

    int ga0 = off + m0 + wave * 32 + lrow;        // per-lane clamp (see ffn1)
    int ga1 = ga0 + 16;
    if (ga0 >= N_POS) ga0 = N_POS - 1;
    if (ga1 >= N_POS) ga1 = N_POS - 1;
    const unsigned short* aS0 = Hg + (size_t)ga0 * D_HIDDEN + csw8;
    const unsigned short* aS1 = Hg + (size_t)ga1 * D_HIDDEN + csw8;
    const unsigned short* bS0 = w2b + (size_t)e * D_HIDDEN * D_MODEL
                              + (size_t)(n0 + wave * 32 + lrow) * D_HIDDEN + csw8;
    const unsigned short* bS1 = bS0 + (size_t)16 * D_HIDDEN;
    unsigned short* aD0 = &As[(wave * 32) * 32];
    unsigned short* aD1 = &As[(wave * 32 + 16) * 32];
    unsigned short* bD0 = &Bs[(wave * 32) * 32];
    unsigned short* bD1 = &Bs[(wave * 32 + 16) * 32];

    f32x4 acc[4][4] = {};
    int wm = (wave & 1) * 64, wn = (wave >> 1) * 64;
    int lane15 = lane & 15, quad = lane >> 4;
    int fro = (quad ^ ((lane15 >> 1) & 3)) * 8;

    for (int k0 = 0; k0 < D_HIDDEN; k0 += 64) {
        #pragma unroll
        for (int h = 0; h < 2; ++h) {
            int ko = k0 + h * 32;
            async_ld16(aS0 + ko, aD0 + h * 4096);
            async_ld16(aS1 + ko, aD1 + h * 4096);
            async_ld16(bS0 + ko, bD0 + h * 4096);
            async_ld16(bS1 + ko, bD1 + h * 4096);
        }
        __syncthreads();
        bf16x8 af[2][4], bf[2][4];
        #pragma unroll
        for (int h = 0; h < 2; ++h)
            #pragma unroll
            for (int t = 0; t < 4; ++t) {
                af[h][t] = *(const bf16x8*)&As[h * 4096 + (wm + t * 16 + lane15) * 32 + fro];
                bf[h][t] = *(const bf16x8*)&Bs[h * 4096 + (wn + t * 16 + lane15) * 32 + fro];
            }
        #pragma unroll
        for (int h = 0; h < 2; ++h)
            #pragma unroll
            for (int i = 0; i < 4; ++i)
                #pragma unroll
                for (int j = 0; j < 4; ++j)
                    acc[i][j] = __builtin_amdgcn_mfma_f32_16x16x32_bf16(
                        af[h][i], bf[h][j], acc[i][j], 0, 0, 0);
        __syncthreads();
    }

    if (tid < 128) {
        int pos = off + m0 + tid;
        if (pos > N_POS - 1) pos = N_POS - 1;
        ptok[tid] = pos2tok[pos];
        psc[tid]  = pos2score[pos];
    }
    __syncthreads();

    #pragma unroll
    for (int j = 0; j < 4; ++j) {
        int gcol = n0 + wn + j * 16 + lane15;
        #pragma unroll
        for (int i = 0; i < 4; ++i) {
            int rowb = wm + i * 16 + quad * 4;
            #pragma unroll
            for (int r = 0; r < 4; ++r) {
                int row = rowb + r;
                if (m0 + row < Ne) {
                    atomicAdd(&out[(size_t)ptok[row] * D_MODEL + gcol],
                              psc[row] * acc[i][j][r]);
                }
            }
        }
    }
}

// ---------------------------------------------------------------------------
extern "C" void kernel_launch(void* const* d_in, const int* in_sizes, int n_in,
                              void* d_out, int out_size, void* d_ws, size_t ws_size,
                              hipStream_t stream) {
    const float* inp    = (const float*)d_in[0];
    const float* gate_w = (const float*)d_in[1];
    const float* gate_b = (const float*)d_in[2];
    const float* w1     = (const float*)d_in[3];
    const float* b1     = (const float*)d_in[4];
    const float* w2     = (const float*)d_in[5];
    const float* b2     = (const float*)d_in[6];
    float* out = (float*)d_out;

    char* ws = (char*)d_ws;
    unsigned short* w1b = (unsigned short*)(ws);                 // 16 MB
    unsigned short* w2b = (unsigned short*)(ws + 16777216);      // 16 MB
    unsigned short* Hg  = (unsigned short*)(ws + 33554432);      // 16 MB
    int*   cnts    = (int*)  (ws + 50331648);                    // 32 B (pad 128)
    int*   emeta   = (int*)  (ws + 50331776);                    // 16 KB
    float* stok    = (float*)(ws + 50348160);                    // 32 KB
    int*   pos2tok = (int*)  (ws + 50380928);                    // 32 KB
    float* pos2sc  = (float*)(ws + 50413696);                    // 32 KB

    // Ag (expert-sorted bf16 activations) lives in d_out: exactly 16 MB.
    unsigned short* Ag = (unsigned short*)d_out;

    hipMemsetAsync(cnts, 0, N_EXPERT * sizeof(int), stream);
    convert_transpose_kernel<<<dim3(16, 16, 16), 256, 0, stream>>>(w1, w2, w1b, w2b);
    gate_kernel<<<dim3(N_TOKENS / 16), 256, 0, stream>>>(
        inp, gate_w, gate_b, cnts, emeta, stok);
    gather_kernel<<<dim3(N_TOKENS / 4), 256, 0, stream>>>(
        inp, cnts, emeta, stok, Ag, pos2tok, pos2sc);
    ffn1_kernel<<<dim3(2048), 256, 0, stream>>>(Ag, w1b, b1, cnts, Hg);
    out_init_kernel<<<dim3(N_TOKENS / 4), 256, 0, stream>>>(emeta, stok, b2, out);
    ffn2_kernel<<<dim3(2048), 256, 0, stream>>>(Hg, w2b, cnts, pos2tok, pos2sc, out);
}

// Round 5
// 227.725 us; speedup vs baseline: 2.1586x; 1.1072x over previous
//
#include <hip/hip_runtime.h>
#include <math.h>

#define N_TOKENS 4096
#define D_MODEL  1024
#define N_EXPERT 8
#define D_HIDDEN 1024
#define N_POS    8192   // N_TOKENS * TOP_K

typedef __bf16 bf16x8 __attribute__((ext_vector_type(8)));
typedef float  f32x4  __attribute__((ext_vector_type(4)));
typedef unsigned short u16x8 __attribute__((ext_vector_type(8)));

#define GLOBAL_AS __attribute__((address_space(1)))
#define LDS_AS    __attribute__((address_space(3)))

static __device__ __forceinline__ void async_ld16(const void* g, void* l) {
    __builtin_amdgcn_global_load_lds((GLOBAL_AS void*)g, (LDS_AS void*)l, 16, 0, 0);
}

static __device__ __forceinline__ unsigned short f2bf(float f) {
    unsigned int u = __builtin_bit_cast(unsigned int, f);
    u += 0x7fffu + ((u >> 16) & 1u);      // round-to-nearest-even
    return (unsigned short)(u >> 16);
}
static __device__ __forceinline__ unsigned int pack2(float a, float b) {
    return (unsigned int)f2bf(a) | ((unsigned int)f2bf(b) << 16);
}
static __device__ __forceinline__ float bflo(unsigned int u) {
    return __builtin_bit_cast(float, u << 16);
}
static __device__ __forceinline__ float bfhi(unsigned int u) {
    return __builtin_bit_cast(float, u & 0xffff0000u);
}

// ---------------------------------------------------------------------------
// fp32 -> bf16 transposed weight convert. src [K][N] -> dst [N][K] k-contig.
// Writes remapped to 64-B full-line chunks per wave (R4 wrote 64 scattered
// 16-B stores per wave at 2-KB stride); cost: 4-way LDS read conflict (1.58x).
// ---------------------------------------------------------------------------
__global__ __launch_bounds__(256) void convert_transpose_kernel(
    const float* __restrict__ w1, const float* __restrict__ w2,
    unsigned short* __restrict__ w1b, unsigned short* __restrict__ w2b)
{
    int mat = blockIdx.z;   // 0..7: w1 experts, 8..15: w2 experts
    const float* src = (mat < 8) ? (w1 + (size_t)mat * 1048576)
                                 : (w2 + (size_t)(mat - 8) * 1048576);
    unsigned short* dst = (mat < 8) ? (w1b + (size_t)mat * 1048576)
                                    : (w2b + (size_t)(mat - 8) * 1048576);
    __shared__ float tile[64][68];
    int r0 = blockIdx.x * 64, c0 = blockIdx.y * 64;
    int tid = threadIdx.x;
    #pragma unroll
    for (int i = 0; i < 4; ++i) {
        int r = (tid >> 4) + i * 16;
        float4 v = *(const float4*)(src + (size_t)(r0 + r) * 1024 + c0 + (tid & 15) * 4);
        *(float4*)&tile[r][(tid & 15) * 4] = v;
    }
    __syncthreads();
    int dr = tid >> 2;                     // dst row in tile (= src col)
    #pragma unroll
    for (int p = 0; p < 2; ++p) {
        int ch = (tid & 3) + p * 4;        // 8-elem chunk of the 64 src rows
        u16x8 o;
        #pragma unroll
        for (int j = 0; j < 8; ++j) o[j] = f2bf(tile[ch * 8 + j][dr]);
        *(u16x8*)(dst + (size_t)(c0 + dr) * 1024 + r0 + ch * 8) = o;
    }
}

// ---------------------------------------------------------------------------
// Gate: fp32-exact top-2 + softmax. Block-aggregated ranking (R4 structure).
// ---------------------------------------------------------------------------
__global__ __launch_bounds__(256) void gate_kernel(
    const float* __restrict__ inp, const float* __restrict__ gate_w,
    const float* __restrict__ gate_b, int* __restrict__ cnts,
    int* __restrict__ emeta, float* __restrict__ stok)
{
    __shared__ int bcnt[8], base[8];
    __shared__ int tinfo[16];   // e0 | e1<<4 | r0<<8 | r1<<20 (block-local)
    int tid = threadIdx.x, lane = tid & 63, wave = tid >> 6;
    if (tid < 8) bcnt[tid] = 0;
    __syncthreads();

    for (int t = 0; t < 4; ++t) {
        int ti = wave * 4 + t;
        int n  = blockIdx.x * 16 + ti;
        const float* ip = inp + (size_t)n * D_MODEL;
        float acc[8] = {0.f,0.f,0.f,0.f,0.f,0.f,0.f,0.f};
        for (int d0 = lane * 4; d0 < D_MODEL; d0 += 256) {
            float4 x = *(const float4*)(ip + d0);
            #pragma unroll
            for (int j = 0; j < 4; ++j) {
                float xv = (j == 0) ? x.x : (j == 1) ? x.y : (j == 2) ? x.z : x.w;
                float4 g0 = *(const float4*)(gate_w + (d0 + j) * 8);
                float4 g1 = *(const float4*)(gate_w + (d0 + j) * 8 + 4);
                acc[0] += xv * g0.x; acc[1] += xv * g0.y;
                acc[2] += xv * g0.z; acc[3] += xv * g0.w;
                acc[4] += xv * g1.x; acc[5] += xv * g1.y;
                acc[6] += xv * g1.z; acc[7] += xv * g1.w;
            }
        }
        #pragma unroll
        for (int off = 32; off > 0; off >>= 1)
            #pragma unroll
            for (int e = 0; e < 8; ++e)
                acc[e] += __shfl_xor(acc[e], off, 64);
        #pragma unroll
        for (int e = 0; e < 8; ++e) acc[e] += gate_b[e];

        // top-2; strictly-greater => lowest index wins ties (lax.top_k)
        int e0 = 0; float v0 = acc[0];
        #pragma unroll
        for (int e = 1; e < 8; ++e) if (acc[e] > v0) { v0 = acc[e]; e0 = e; }
        int e1 = -1; float v1 = -1e30f;
        #pragma unroll
        for (int e = 0; e < 8; ++e) if (e != e0 && acc[e] > v1) { v1 = acc[e]; e1 = e; }
        float tv = expf(v1 - v0);
        float s0 = 1.0f / (1.0f + tv);
        float s1 = tv / (1.0f + tv);

        if (lane == 0) {
            int r0 = atomicAdd(&bcnt[e0], 1);   // LDS atomic: block-local rank
            int r1 = atomicAdd(&bcnt[e1], 1);
            tinfo[ti] = e0 | (e1 << 4) | (r0 << 8) | (r1 << 20);
            stok[2 * n]     = s0;
            stok[2 * n + 1] = s1;
        }
    }
    __syncthreads();
    if (tid < 8) base[tid] = atomicAdd(&cnts[tid], bcnt[tid]);  // 8 globals/block
    __syncthreads();
    if (tid < 16) {
        int n = blockIdx.x * 16 + tid;
        unsigned int inf = (unsigned int)tinfo[tid];
        int e0 = inf & 15, e1 = (inf >> 4) & 15;
        int p0 = base[e0] + ((inf >> 8) & 4095);
        int p1 = base[e1] + (int)(inf >> 20);
        emeta[n] = e0 | (e1 << 4) | (p0 << 8) | (p1 << 20);
    }
}

// ---------------------------------------------------------------------------
// Gather: expert-sorted bf16 activation matrix Ag[N_POS][D_MODEL] (in d_out)
// + token -> position map (for the combine pass).
// ---------------------------------------------------------------------------
__global__ __launch_bounds__(256) void gather_kernel(
    const float* __restrict__ inp, const int* __restrict__ cnts,
    const int* __restrict__ emeta, unsigned short* __restrict__ Ag,
    int* __restrict__ tok2pos)
{
    int lane = threadIdx.x & 63, wave = threadIdx.x >> 6;
    int n = blockIdx.x * 4 + wave;
    unsigned int em = (unsigned int)emeta[n];
    int e0 = em & 15, e1 = (em >> 4) & 15;
    int p0 = (em >> 8) & 4095, p1 = (int)(em >> 20);
    int off0 = 0, off1 = 0;
    #pragma unroll
    for (int e = 0; e < 8; ++e) {
        int c = cnts[e];
        off0 += (e < e0) ? c : 0;
        off1 += (e < e1) ? c : 0;
    }
    int pos0 = off0 + p0, pos1 = off1 + p1;
    if (lane == 0) {
        tok2pos[2 * n]     = pos0;
        tok2pos[2 * n + 1] = pos1;
    }
    const float* ip = inp + (size_t)n * D_MODEL;
    unsigned short* r0 = Ag + (size_t)pos0 * D_MODEL;
    unsigned short* r1 = Ag + (size_t)pos1 * D_MODEL;
    for (int d = lane * 4; d < D_MODEL; d += 256) {
        float4 v = *(const float4*)(ip + d);
        uint2 u; u.x = pack2(v.x, v.y); u.y = pack2(v.z, v.w);
        *(uint2*)(r0 + d) = u;
        *(uint2*)(r1 + d) = u;
    }
}

// ---------------------------------------------------------------------------
// Grouped GEMM1: Hg[pos] = gelu( Ag[pos] @ w1b[e]^T + b1[e] )
// 128x128 tile, BK=64, all-async staging, per-lane source-row clamp.
// ---------------------------------------------------------------------------
__global__ __launch_bounds__(256, 2) void ffn1_kernel(
    const unsigned short* __restrict__ Ag, const unsigned short* __restrict__ w1b,
    const float* __restrict__ b1, const int* __restrict__ cnts,
    unsigned short* __restrict__ Hg)
{
    int bid = blockIdx.x;
    int e = bid & 7, nt = (bid >> 3) & 7, mt = bid >> 6;
    int off = 0, Ne = 0;
    #pragma unroll
    for (int i = 0; i < 8; ++i) {
        int c = cnts[i];
        off += (i < e) ? c : 0;
        Ne = (i == e) ? c : Ne;
    }
    int m0 = mt * 128;
    if (m0 >= Ne) return;
    int n0 = nt * 128;

    __shared__ unsigned short As[2 * 128 * 32];   // [half][row][32], chunk-swizzled
    __shared__ unsigned short Bs[2 * 128 * 32];

    int tid = threadIdx.x, lane = tid & 63, wave = tid >> 6;
    int lrow = lane >> 2, lchunk = lane & 3;
    int csw8 = (lchunk ^ ((lrow >> 1) & 3)) * 8;

    int ga0 = off + m0 + wave * 32 + lrow;        // per-lane global source row
    int ga1 = ga0 + 16;
    if (ga0 >= N_POS) ga0 = N_POS - 1;            // rows >= segment end are
    if (ga1 >= N_POS) ga1 = N_POS - 1;            // masked in the epilogue
    const unsigned short* aS0 = Ag + (size_t)ga0 * D_MODEL + csw8;
    const unsigned short* aS1 = Ag + (size_t)ga1 * D_MODEL + csw8;
    const unsigned short* bS0 = w1b + (size_t)e * D_MODEL * D_HIDDEN
                              + (size_t)(n0 + wave * 32 + lrow) * D_MODEL + csw8;
    const unsigned short* bS1 = bS0 + (size_t)16 * D_MODEL;
    unsigned short* aD0 = &As[(wave * 32) * 32];
    unsigned short* aD1 = &As[(wave * 32 + 16) * 32];
    unsigned short* bD0 = &Bs[(wave * 32) * 32];
    unsigned short* bD1 = &Bs[(wave * 32 + 16) * 32];

    f32x4 acc[4][4] = {};
    int wm = (wave & 1) * 64, wn = (wave >> 1) * 64;
    int lane15 = lane & 15, quad = lane >> 4;
    int fro = (quad ^ ((lane15 >> 1) & 3)) * 8;

    for (int k0 = 0; k0 < D_MODEL; k0 += 64) {
        #pragma unroll
        for (int h = 0; h < 2; ++h) {
            int ko = k0 + h * 32;
            async_ld16(aS0 + ko, aD0 + h * 4096);
            async_ld16(aS1 + ko, aD1 + h * 4096);
            async_ld16(bS0 + ko, bD0 + h * 4096);
            async_ld16(bS1 + ko, bD1 + h * 4096);
        }
        __syncthreads();
        bf16x8 af[2][4], bf[2][4];
        #pragma unroll
        for (int h = 0; h < 2; ++h)
            #pragma unroll
            for (int t = 0; t < 4; ++t) {
                af[h][t] = *(const bf16x8*)&As[h * 4096 + (wm + t * 16 + lane15) * 32 + fro];
                bf[h][t] = *(const bf16x8*)&Bs[h * 4096 + (wn + t * 16 + lane15) * 32 + fro];
            }
        #pragma unroll
        for (int h = 0; h < 2; ++h)
            #pragma unroll
            for (int i = 0; i < 4; ++i)
                #pragma unroll
                for (int j = 0; j < 4; ++j)
                    acc[i][j] = __builtin_amdgcn_mfma_f32_16x16x32_bf16(
                        af[h][i], bf[h][j], acc[i][j], 0, 0, 0);
        __syncthreads();
    }

    const float* bexp = b1 + (size_t)e * D_HIDDEN;
    #pragma unroll
    for (int j = 0; j < 4; ++j) {
        int gcol = n0 + wn + j * 16 + lane15;
        float bv = bexp[gcol];
        #pragma unroll
        for (int i = 0; i < 4; ++i) {
            int rowb = wm + i * 16 + quad * 4;
            #pragma unroll
            for (int r = 0; r < 4; ++r) {
                int row = rowb + r;
                if (m0 + row < Ne) {
                    float x = acc[i][j][r] + bv;
                    float gv = 0.5f * x * (1.0f + erff(x * 0.70710678118654752f));
                    Hg[(size_t)(off + m0 + row) * D_HIDDEN + gcol] = f2bf(gv);
                }
            }
        }
    }
}

// ---------------------------------------------------------------------------
// Grouped GEMM2: Og[pos] = Hg[pos] @ w2b[e]^T   (bf16, plain stores — the
// R4 atomic epilogue serialized 8.4M cross-XCD RMWs; scale+bias+combine is
// deferred to combine_kernel)
// ---------------------------------------------------------------------------
__global__ __launch_bounds__(256, 2) void ffn2_kernel(
    const unsigned short* __restrict__ Hg, const unsigned short* __restrict__ w2b,
    const int* __restrict__ cnts, unsigned short* __restrict__ Og)
{
    int bid = blockIdx.x;
    int e = bid & 7, nt = (bid >> 3) & 7, mt = bid >> 6;
    int off = 0, Ne = 0;
    #pragma unroll
    for (int i = 0; i < 8; ++i) {
        int c = cnts[i];
        off += (i < e) ? c : 0;
        Ne = (i == e) ? c : Ne;
    }
    int m0 = mt * 128;
    if (m0 >= Ne) return;
    int n0 = nt * 128;

    __shared__ unsigned short As[2 * 128 * 32];
    __shared__ unsigned short Bs[2 * 128 * 32];

    int tid = threadIdx.x, lane = tid & 63, wave = tid >> 6;
    int lrow = lane >> 2, lchunk = lane & 3;
    int csw8 = (lchunk ^ ((lrow >> 1) & 3)) * 8;

    int ga0 = off + m0 + wave * 32 + lrow;        // per-lane clamp (see ffn1)
    int ga1 = ga0 + 16;
    if (ga0 >= N_POS) ga0 = N_POS - 1;
    if (ga1 >= N_POS) ga1 = N_POS - 1;
    const unsigned short* aS0 = Hg + (size_t)ga0 * D_HIDDEN + csw8;
    const unsigned short* aS1 = Hg + (size_t)ga1 * D_HIDDEN + csw8;
    const unsigned short* bS0 = w2b + (size_t)e * D_HIDDEN * D_MODEL
                              + (size_t)(n0 + wave * 32 + lrow) * D_HIDDEN + csw8;
    const unsigned short* bS1 = bS0 + (size_t)16 * D_HIDDEN;
    unsigned short* aD0 = &As[(wave * 32) * 32];
    unsigned short* aD1 = &As[(wave * 32 + 16) * 32];
    unsigned short* bD0 = &Bs[(wave * 32) * 32];
    unsigned short* bD1 = &Bs[(wave * 32 + 16) * 32];

    f32x4 acc[4][4] = {};
    int wm = (wave & 1) * 64, wn = (wave >> 1) * 64;
    int lane15 = lane & 15, quad = lane >> 4;
    int fro = (quad ^ ((lane15 >> 1) & 3)) * 8;

    for (int k0 = 0; k0 < D_HIDDEN; k0 += 64) {
        #pragma unroll
        for (int h = 0; h < 2; ++h) {
            int ko = k0 + h * 32;
            async_ld16(aS0 + ko, aD0 + h * 4096);
            async_ld16(aS1 + ko, aD1 + h * 4096);
            async_ld16(bS0 + ko, bD0 + h * 4096);
            async_ld16(bS1 + ko, bD1 + h * 4096);
        }
        __syncthreads();
        bf16x8 af[2][4], bf[2][4];
        #pragma unroll
        for (int h = 0; h < 2; ++h)
            #pragma unroll
            for (int t = 0; t < 4; ++t) {
                af[h][t] = *(const bf16x8*)&As[h * 4096 + (wm + t * 16 + lane15) * 32 + fro];
                bf[h][t] = *(const bf16x8*)&Bs[h * 4096 + (wn + t * 16 + lane15) * 32 + fro];
            }
        #pragma unroll
        for (int h = 0; h < 2; ++h)
            #pragma unroll
            for (int i = 0; i < 4; ++i)
                #pragma unroll
                for (int j = 0; j < 4; ++j)
                    acc[i][j] = __builtin_amdgcn_mfma_f32_16x16x32_bf16(
                        af[h][i], bf[h][j], acc[i][j], 0, 0, 0);
        __syncthreads();
    }

    #pragma unroll
    for (int j = 0; j < 4; ++j) {
        int gcol = n0 + wn + j * 16 + lane15;
        #pragma unroll
        for (int i = 0; i < 4; ++i) {
            int rowb = wm + i * 16 + quad * 4;
            #pragma unroll
            for (int r = 0; r < 4; ++r) {
                int row = rowb + r;
                if (m0 + row < Ne) {
                    Og[(size_t)(off + m0 + row) * D_MODEL + gcol] =
                        f2bf(acc[i][j][r]);
                }
            }
        }
    }
}

// ---------------------------------------------------------------------------
// Combine: out[n] = s0*(Og[pos0]+b2[e0]) + s1*(Og[pos1]+b2[e1])
// ---------------------------------------------------------------------------
__global__ __launch_bounds__(256) void combine_kernel(
    const unsigned short* __restrict__ Og, const int* __restrict__ tok2pos,
    const float* __restrict__ stok, const int* __restrict__ emeta,
    const float* __restrict__ b2, float* __restrict__ out)
{
    int lane = threadIdx.x & 63, wave = threadIdx.x >> 6;
    int n = blockIdx.x * 4 + wave;
    int pos0 = tok2pos[2 * n], pos1 = tok2pos[2 * n + 1];
    float s0 = stok[2 * n], s1 = stok[2 * n + 1];
    unsigned int em = (unsigned int)emeta[n];
    int e0 = em & 15, e1 = (em >> 4) & 15;
    const unsigned short* o0 = Og + (size_t)pos0 * D_MODEL;
    const unsigned short* o1 = Og + (size_t)pos1 * D_MODEL;
    const float* bA = b2 + (size_t)e0 * D_MODEL;
    const float* bB = b2 + (size_t)e1 * D_MODEL;
    float* op = out + (size_t)n * D_MODEL;
    for (int d = lane * 4; d < D_MODEL; d += 256) {
        uint2 u0 = *(const uint2*)(o0 + d);
        uint2 u1 = *(const uint2*)(o1 + d);
        float4 xa = *(const float4*)(bA + d);
        float4 xb = *(const float4*)(bB + d);
        float4 r;
        r.x = s0 * (bflo(u0.x) + xa.x) + s1 * (bflo(u1.x) + xb.x);
        r.y = s0 * (bfhi(u0.x) + xa.y) + s1 * (bfhi(u1.x) + xb.y);
        r.z = s0 * (bflo(u0.y) + xa.z) + s1 * (bflo(u1.y) + xb.z);
        r.w = s0 * (bfhi(u0.y) + xa.w) + s1 * (bfhi(u1.y) + xb.w);
        *(float4*)(op + d) = r;
    }
}

// ---------------------------------------------------------------------------
extern "C" void kernel_launch(void* const* d_in, const int* in_sizes, int n_in,
                              void* d_out, int out_size, void* d_ws, size_t ws_size,
                              hipStream_t stream) {
    const float* inp    = (const float*)d_in[0];
    const float* gate_w = (const float*)d_in[1];
    const float* gate_b = (const float*)d_in[2];
    const float* w1     = (const float*)d_in[3];
    const float* b1     = (const float*)d_in[4];
    const float* w2     = (const float*)d_in[5];
    const float* b2     = (const float*)d_in[6];
    float* out = (float*)d_out;

    // ws layout (Og aliases w1b: w1b dead after ffn1, Og written in ffn2;
    // both are exactly 16 MiB). Total usage: 33 MiB meta+w2b+Hg base + 16 MiB
    // = 49 MiB, within the footprint proven in R4.
    char* ws = (char*)d_ws;
    int*   cnts    = (int*)  (ws);                               // 128 B
    int*   emeta   = (int*)  (ws + 4096);                        // 16 KB
    float* stok    = (float*)(ws + 65536);                       // 32 KB
    int*   tok2pos = (int*)  (ws + 131072);                      // 32 KB
    unsigned short* w2b = (unsigned short*)(ws + 1048576);       // 16 MiB
    unsigned short* Hg  = (unsigned short*)(ws + 17825792);      // 16 MiB
    unsigned short* w1b = (unsigned short*)(ws + 34603008);      // 16 MiB
    unsigned short* Og  = (unsigned short*)(ws + 34603008);      // aliases w1b

    // Ag (expert-sorted bf16 activations) lives in d_out (16 MiB); d_out is
    // rewritten by combine_kernel at the end.
    unsigned short* Ag = (unsigned short*)d_out;

    hipMemsetAsync(cnts, 0, N_EXPERT * sizeof(int), stream);
    convert_transpose_kernel<<<dim3(16, 16, 16), 256, 0, stream>>>(w1, w2, w1b, w2b);
    gate_kernel<<<dim3(N_TOKENS / 16), 256, 0, stream>>>(
        inp, gate_w, gate_b, cnts, emeta, stok);
    gather_kernel<<<dim3(N_TOKENS / 4), 256, 0, stream>>>(
        inp, cnts, emeta, Ag, tok2pos);
    ffn1_kernel<<<dim3(2048), 256, 0, stream>>>(Ag, w1b, b1, cnts, Hg);
    ffn2_kernel<<<dim3(2048), 256, 0, stream>>>(Hg, w2b, cnts, Og);
    combine_kernel<<<dim3(N_TOKENS / 4), 256, 0, stream>>>(
        Og, tok2pos, stok, emeta, b2, out);
}

// Round 6
// 224.944 us; speedup vs baseline: 2.1853x; 1.0124x over previous
//
#include <hip/hip_runtime.h>
#include <math.h>

#define N_TOKENS 4096
#define D_MODEL  1024
#define N_EXPERT 8
#define D_HIDDEN 1024
#define N_POS    8192   // N_TOKENS * TOP_K

typedef __bf16 bf16x8 __attribute__((ext_vector_type(8)));
typedef float  f32x4  __attribute__((ext_vector_type(4)));
typedef unsigned short u16x8 __attribute__((ext_vector_type(8)));

#define GLOBAL_AS __attribute__((address_space(1)))
#define LDS_AS    __attribute__((address_space(3)))

static __device__ __forceinline__ void async_ld16(const void* g, void* l) {
    __builtin_amdgcn_global_load_lds((GLOBAL_AS void*)g, (LDS_AS void*)l, 16, 0, 0);
}

static __device__ __forceinline__ unsigned short f2bf(float f) {
    unsigned int u = __builtin_bit_cast(unsigned int, f);
    u += 0x7fffu + ((u >> 16) & 1u);      // round-to-nearest-even
    return (unsigned short)(u >> 16);
}
static __device__ __forceinline__ unsigned int pack2(float a, float b) {
    return (unsigned int)f2bf(a) | ((unsigned int)f2bf(b) << 16);
}
static __device__ __forceinline__ float bflo(unsigned int u) {
    return __builtin_bit_cast(float, u << 16);
}
static __device__ __forceinline__ float bfhi(unsigned int u) {
    return __builtin_bit_cast(float, u & 0xffff0000u);
}

// ---------------------------------------------------------------------------
// fp32 -> bf16 transposed weight convert. src [K][N] -> dst [N][K] k-contig.
// ---------------------------------------------------------------------------
__global__ __launch_bounds__(256) void convert_transpose_kernel(
    const float* __restrict__ w1, const float* __restrict__ w2,
    unsigned short* __restrict__ w1b, unsigned short* __restrict__ w2b)
{
    int mat = blockIdx.z;   // 0..7: w1 experts, 8..15: w2 experts
    const float* src = (mat < 8) ? (w1 + (size_t)mat * 1048576)
                                 : (w2 + (size_t)(mat - 8) * 1048576);
    unsigned short* dst = (mat < 8) ? (w1b + (size_t)mat * 1048576)
                                    : (w2b + (size_t)(mat - 8) * 1048576);
    __shared__ float tile[64][68];
    int r0 = blockIdx.x * 64, c0 = blockIdx.y * 64;
    int tid = threadIdx.x;
    #pragma unroll
    for (int i = 0; i < 4; ++i) {
        int r = (tid >> 4) + i * 16;
        float4 v = *(const float4*)(src + (size_t)(r0 + r) * 1024 + c0 + (tid & 15) * 4);
        *(float4*)&tile[r][(tid & 15) * 4] = v;
    }
    __syncthreads();
    int dr = tid >> 2;                     // dst row in tile (= src col)
    #pragma unroll
    for (int p = 0; p < 2; ++p) {
        int ch = (tid & 3) + p * 4;        // 8-elem chunk of the 64 src rows
        u16x8 o;
        #pragma unroll
        for (int j = 0; j < 8; ++j) o[j] = f2bf(tile[ch * 8 + j][dr]);
        *(u16x8*)(dst + (size_t)(c0 + dr) * 1024 + r0 + ch * 8) = o;
    }
}

// ---------------------------------------------------------------------------
// Gate: fp32-exact top-2 + softmax. Block-aggregated ranking.
// ---------------------------------------------------------------------------
__global__ __launch_bounds__(256) void gate_kernel(
    const float* __restrict__ inp, const float* __restrict__ gate_w,
    const float* __restrict__ gate_b, int* __restrict__ cnts,
    int* __restrict__ emeta, float* __restrict__ stok)
{
    __shared__ int bcnt[8], base[8];
    __shared__ int tinfo[16];   // e0 | e1<<4 | r0<<8 | r1<<20 (block-local)
    int tid = threadIdx.x, lane = tid & 63, wave = tid >> 6;
    if (tid < 8) bcnt[tid] = 0;
    __syncthreads();

    for (int t = 0; t < 4; ++t) {
        int ti = wave * 4 + t;
        int n  = blockIdx.x * 16 + ti;
        const float* ip = inp + (size_t)n * D_MODEL;
        float acc[8] = {0.f,0.f,0.f,0.f,0.f,0.f,0.f,0.f};
        for (int d0 = lane * 4; d0 < D_MODEL; d0 += 256) {
            float4 x = *(const float4*)(ip + d0);
            #pragma unroll
            for (int j = 0; j < 4; ++j) {
                float xv = (j == 0) ? x.x : (j == 1) ? x.y : (j == 2) ? x.z : x.w;
                float4 g0 = *(const float4*)(gate_w + (d0 + j) * 8);
                float4 g1 = *(const float4*)(gate_w + (d0 + j) * 8 + 4);
                acc[0] += xv * g0.x; acc[1] += xv * g0.y;
                acc[2] += xv * g0.z; acc[3] += xv * g0.w;
                acc[4] += xv * g1.x; acc[5] += xv * g1.y;
                acc[6] += xv * g1.z; acc[7] += xv * g1.w;
            }
        }
        #pragma unroll
        for (int off = 32; off > 0; off >>= 1)
            #pragma unroll
            for (int e = 0; e < 8; ++e)
                acc[e] += __shfl_xor(acc[e], off, 64);
        #pragma unroll
        for (int e = 0; e < 8; ++e) acc[e] += gate_b[e];

        // top-2; strictly-greater => lowest index wins ties (lax.top_k)
        int e0 = 0; float v0 = acc[0];
        #pragma unroll
        for (int e = 1; e < 8; ++e) if (acc[e] > v0) { v0 = acc[e]; e0 = e; }
        int e1 = -1; float v1 = -1e30f;
        #pragma unroll
        for (int e = 0; e < 8; ++e) if (e != e0 && acc[e] > v1) { v1 = acc[e]; e1 = e; }
        float tv = expf(v1 - v0);
        float s0 = 1.0f / (1.0f + tv);
        float s1 = tv / (1.0f + tv);

        if (lane == 0) {
            int r0 = atomicAdd(&bcnt[e0], 1);   // LDS atomic: block-local rank
            int r1 = atomicAdd(&bcnt[e1], 1);
            tinfo[ti] = e0 | (e1 << 4) | (r0 << 8) | (r1 << 20);
            stok[2 * n]     = s0;
            stok[2 * n + 1] = s1;
        }
    }
    __syncthreads();
    if (tid < 8) base[tid] = atomicAdd(&cnts[tid], bcnt[tid]);  // 8 globals/block
    __syncthreads();
    if (tid < 16) {
        int n = blockIdx.x * 16 + tid;
        unsigned int inf = (unsigned int)tinfo[tid];
        int e0 = inf & 15, e1 = (inf >> 4) & 15;
        int p0 = base[e0] + ((inf >> 8) & 4095);
        int p1 = base[e1] + (int)(inf >> 20);
        emeta[n] = e0 | (e1 << 4) | (p0 << 8) | (p1 << 20);
    }
}

// ---------------------------------------------------------------------------
// Gather: expert-sorted bf16 activation matrix Ag[N_POS][D_MODEL] (in d_out)
// + token -> position map.
// ---------------------------------------------------------------------------
__global__ __launch_bounds__(256) void gather_kernel(
    const float* __restrict__ inp, const int* __restrict__ cnts,
    const int* __restrict__ emeta, unsigned short* __restrict__ Ag,
    int* __restrict__ tok2pos)
{
    int lane = threadIdx.x & 63, wave = threadIdx.x >> 6;
    int n = blockIdx.x * 4 + wave;
    unsigned int em = (unsigned int)emeta[n];
    int e0 = em & 15, e1 = (em >> 4) & 15;
    int p0 = (em >> 8) & 4095, p1 = (int)(em >> 20);
    int off0 = 0, off1 = 0;
    #pragma unroll
    for (int e = 0; e < 8; ++e) {
        int c = cnts[e];
        off0 += (e < e0) ? c : 0;
        off1 += (e < e1) ? c : 0;
    }
    int pos0 = off0 + p0, pos1 = off1 + p1;
    if (lane == 0) {
        tok2pos[2 * n]     = pos0;
        tok2pos[2 * n + 1] = pos1;
    }
    const float* ip = inp + (size_t)n * D_MODEL;
    unsigned short* r0 = Ag + (size_t)pos0 * D_MODEL;
    unsigned short* r1 = Ag + (size_t)pos1 * D_MODEL;
    for (int d = lane * 4; d < D_MODEL; d += 256) {
        float4 v = *(const float4*)(ip + d);
        uint2 u; u.x = pack2(v.x, v.y); u.y = pack2(v.z, v.w);
        *(uint2*)(r0 + d) = u;
        *(uint2*)(r1 + d) = u;
    }
}

// ---------------------------------------------------------------------------
// Grouped GEMM1: Hg[pos] = gelu( Ag[pos] @ w1b[e]^T + b1[e] )
// R6: 128x64 tile (was 128x128) -> ~1024 active blocks = 4/CU (was 512 = 2/CU,
// occupancy 17%, latency-bound). Waves 2x2, each 64x32, acc 4x2 (32 AGPRs).
// LDS 24 KB/block; same swizzle/clamp scheme as the verified R5 kernel.
// ---------------------------------------------------------------------------
__global__ __launch_bounds__(256, 4) void ffn1_kernel(
    const unsigned short* __restrict__ Ag, const unsigned short* __restrict__ w1b,
    const float* __restrict__ b1, const int* __restrict__ cnts,
    unsigned short* __restrict__ Hg)
{
    int bid = blockIdx.x;
    int e = bid & 7, nt = (bid >> 3) & 15, mt = bid >> 7;
    int off = 0, Ne = 0;
    #pragma unroll
    for (int i = 0; i < 8; ++i) {
        int c = cnts[i];
        off += (i < e) ? c : 0;
        Ne = (i == e) ? c : Ne;
    }
    int m0 = mt * 128;
    if (m0 >= Ne) return;
    int n0 = nt * 64;

    __shared__ unsigned short As[2 * 128 * 32];   // [half][row][32] 16 KB
    __shared__ unsigned short Bs[2 * 64 * 32];    // [half][row][32]  8 KB

    int tid = threadIdx.x, lane = tid & 63, wave = tid >> 6;
    int lrow = lane >> 2, lchunk = lane & 3;
    int csw8 = (lchunk ^ ((lrow >> 1) & 3)) * 8;

    int ga0 = off + m0 + wave * 32 + lrow;        // per-lane global source row
    int ga1 = ga0 + 16;
    if (ga0 >= N_POS) ga0 = N_POS - 1;            // rows >= segment end are
    if (ga1 >= N_POS) ga1 = N_POS - 1;            // masked in the epilogue
    const unsigned short* aS0 = Ag + (size_t)ga0 * D_MODEL + csw8;
    const unsigned short* aS1 = Ag + (size_t)ga1 * D_MODEL + csw8;
    // B: wave stages rows [wave*16, wave*16+16) of the 64-row tile
    const unsigned short* bS = w1b + (size_t)e * D_MODEL * D_HIDDEN
                             + (size_t)(n0 + wave * 16 + lrow) * D_MODEL + csw8;
    unsigned short* aD0 = &As[(wave * 32) * 32];
    unsigned short* aD1 = &As[(wave * 32 + 16) * 32];
    unsigned short* bD  = &Bs[(wave * 16) * 32];

    f32x4 acc[4][2] = {};
    int wm = (wave & 1) * 64, wn = ((wave >> 1) & 1) * 32;
    int lane15 = lane & 15, quad = lane >> 4;
    int fro = (quad ^ ((lane15 >> 1) & 3)) * 8;

    for (int k0 = 0; k0 < D_MODEL; k0 += 64) {
        #pragma unroll
        for (int h = 0; h < 2; ++h) {
            int ko = k0 + h * 32;
            async_ld16(aS0 + ko, aD0 + h * 4096);
            async_ld16(aS1 + ko, aD1 + h * 4096);
            async_ld16(bS  + ko, bD  + h * 2048);
        }
        __syncthreads();
        #pragma unroll
        for (int h = 0; h < 2; ++h) {
            bf16x8 af[4], bf[2];
            #pragma unroll
            for (int t = 0; t < 4; ++t)
                af[t] = *(const bf16x8*)&As[h * 4096 + (wm + t * 16 + lane15) * 32 + fro];
            #pragma unroll
            for (int t = 0; t < 2; ++t)
                bf[t] = *(const bf16x8*)&Bs[h * 2048 + (wn + t * 16 + lane15) * 32 + fro];
            #pragma unroll
            for (int i = 0; i < 4; ++i)
                #pragma unroll
                for (int j = 0; j < 2; ++j)
                    acc[i][j] = __builtin_amdgcn_mfma_f32_16x16x32_bf16(
                        af[i], bf[j], acc[i][j], 0, 0, 0);
        }
        __syncthreads();
    }

    const float* bexp = b1 + (size_t)e * D_HIDDEN;
    #pragma unroll
    for (int j = 0; j < 2; ++j) {
        int gcol = n0 + wn + j * 16 + lane15;
        float bv = bexp[gcol];
        #pragma unroll
        for (int i = 0; i < 4; ++i) {
            int rowb = wm + i * 16 + quad * 4;
            #pragma unroll
            for (int r = 0; r < 4; ++r) {
                int row = rowb + r;
                if (m0 + row < Ne) {
                    float x = acc[i][j][r] + bv;
                    float gv = 0.5f * x * (1.0f + erff(x * 0.70710678118654752f));
                    Hg[(size_t)(off + m0 + row) * D_HIDDEN + gcol] = f2bf(gv);
                }
            }
        }
    }
}

// ---------------------------------------------------------------------------
// Grouped GEMM2: Og[pos] = Hg[pos] @ w2b[e]^T  (same 128x64 structure)
// ---------------------------------------------------------------------------
__global__ __launch_bounds__(256, 4) void ffn2_kernel(
    const unsigned short* __restrict__ Hg, const unsigned short* __restrict__ w2b,
    const int* __restrict__ cnts, unsigned short* __restrict__ Og)
{
    int bid = blockIdx.x;
    int e = bid & 7, nt = (bid >> 3) & 15, mt = bid >> 7;
    int off = 0, Ne = 0;
    #pragma unroll
    for (int i = 0; i < 8; ++i) {
        int c = cnts[i];
        off += (i < e) ? c : 0;
        Ne = (i == e) ? c : Ne;
    }
    int m0 = mt * 128;
    if (m0 >= Ne) return;
    int n0 = nt * 64;

    __shared__ unsigned short As[2 * 128 * 32];
    __shared__ unsigned short Bs[2 * 64 * 32];

    int tid = threadIdx.x, lane = tid & 63, wave = tid >> 6;
    int lrow = lane >> 2, lchunk = lane & 3;
    int csw8 = (lchunk ^ ((lrow >> 1) & 3)) * 8;

    int ga0 = off + m0 + wave * 32 + lrow;
    int ga1 = ga0 + 16;
    if (ga0 >= N_POS) ga0 = N_POS - 1;
    if (ga1 >= N_POS) ga1 = N_POS - 1;
    const unsigned short* aS0 = Hg + (size_t)ga0 * D_HIDDEN + csw8;
    const unsigned short* aS1 = Hg + (size_t)ga1 * D_HIDDEN + csw8;
    const unsigned short* bS = w2b + (size_t)e * D_HIDDEN * D_MODEL
                             + (size_t)(n0 + wave * 16 + lrow) * D_HIDDEN + csw8;
    unsigned short* aD0 = &As[(wave * 32) * 32];
    unsigned short* aD1 = &As[(wave * 32 + 16) * 32];
    unsigned short* bD  = &Bs[(wave * 16) * 32];

    f32x4 acc[4][2] = {};
    int wm = (wave & 1) * 64, wn = ((wave >> 1) & 1) * 32;
    int lane15 = lane & 15, quad = lane >> 4;
    int fro = (quad ^ ((lane15 >> 1) & 3)) * 8;

    for (int k0 = 0; k0 < D_HIDDEN; k0 += 64) {
        #pragma unroll
        for (int h = 0; h < 2; ++h) {
            int ko = k0 + h * 32;
            async_ld16(aS0 + ko, aD0 + h * 4096);
            async_ld16(aS1 + ko, aD1 + h * 4096);
            async_ld16(bS  + ko, bD  + h * 2048);
        }
        __syncthreads();
        #pragma unroll
        for (int h = 0; h < 2; ++h) {
            bf16x8 af[4], bf[2];
            #pragma unroll
            for (int t = 0; t < 4; ++t)
                af[t] = *(const bf16x8*)&As[h * 4096 + (wm + t * 16 + lane15) * 32 + fro];
            #pragma unroll
            for (int t = 0; t < 2; ++t)
                bf[t] = *(const bf16x8*)&Bs[h * 2048 + (wn + t * 16 + lane15) * 32 + fro];
            #pragma unroll
            for (int i = 0; i < 4; ++i)
                #pragma unroll
                for (int j = 0; j < 2; ++j)
                    acc[i][j] = __builtin_amdgcn_mfma_f32_16x16x32_bf16(
                        af[i], bf[j], acc[i][j], 0, 0, 0);
        }
        __syncthreads();
    }

    #pragma unroll
    for (int j = 0; j < 2; ++j) {
        int gcol = n0 + wn + j * 16 + lane15;
        #pragma unroll
        for (int i = 0; i < 4; ++i) {
            int rowb = wm + i * 16 + quad * 4;
            #pragma unroll
            for (int r = 0; r < 4; ++r) {
                int row = rowb + r;
                if (m0 + row < Ne) {
                    Og[(size_t)(off + m0 + row) * D_MODEL + gcol] =
                        f2bf(acc[i][j][r]);
                }
            }
        }
    }
}

// ---------------------------------------------------------------------------
// Combine: out[n] = s0*(Og[pos0]+b2[e0]) + s1*(Og[pos1]+b2[e1])
// ---------------------------------------------------------------------------
__global__ __launch_bounds__(256) void combine_kernel(
    const unsigned short* __restrict__ Og, const int* __restrict__ tok2pos,
    const float* __restrict__ stok, const int* __restrict__ emeta,
    const float* __restrict__ b2, float* __restrict__ out)
{
    int lane = threadIdx.x & 63, wave = threadIdx.x >> 6;
    int n = blockIdx.x * 4 + wave;
    int pos0 = tok2pos[2 * n], pos1 = tok2pos[2 * n + 1];
    float s0 = stok[2 * n], s1 = stok[2 * n + 1];
    unsigned int em = (unsigned int)emeta[n];
    int e0 = em & 15, e1 = (em >> 4) & 15;
    const unsigned short* o0 = Og + (size_t)pos0 * D_MODEL;
    const unsigned short* o1 = Og + (size_t)pos1 * D_MODEL;
    const float* bA = b2 + (size_t)e0 * D_MODEL;
    const float* bB = b2 + (size_t)e1 * D_MODEL;
    float* op = out + (size_t)n * D_MODEL;
    for (int d = lane * 4; d < D_MODEL; d += 256) {
        uint2 u0 = *(const uint2*)(o0 + d);
        uint2 u1 = *(const uint2*)(o1 + d);
        float4 xa = *(const float4*)(bA + d);
        float4 xb = *(const float4*)(bB + d);
        float4 r;
        r.x = s0 * (bflo(u0.x) + xa.x) + s1 * (bflo(u1.x) + xb.x);
        r.y = s0 * (bfhi(u0.x) + xa.y) + s1 * (bfhi(u1.x) + xb.y);
        r.z = s0 * (bflo(u0.y) + xa.z) + s1 * (bflo(u1.y) + xb.z);
        r.w = s0 * (bfhi(u0.y) + xa.w) + s1 * (bfhi(u1.y) + xb.w);
        *(float4*)(op + d) = r;
    }
}

// ---------------------------------------------------------------------------
extern "C" void kernel_launch(void* const* d_in, const int* in_sizes, int n_in,
                              void* d_out, int out_size, void* d_ws, size_t ws_size,
                              hipStream_t stream) {
    const float* inp    = (const float*)d_in[0];
    const float* gate_w = (const float*)d_in[1];
    const float* gate_b = (const float*)d_in[2];
    const float* w1     = (const float*)d_in[3];
    const float* b1     = (const float*)d_in[4];
    const float* w2     = (const float*)d_in[5];
    const float* b2     = (const float*)d_in[6];
    float* out = (float*)d_out;

    // ws layout (Og aliases w1b: w1b dead after ffn1, Og written in ffn2).
    char* ws = (char*)d_ws;
    int*   cnts    = (int*)  (ws);                               // 128 B
    int*   emeta   = (int*)  (ws + 4096);                        // 16 KB
    float* stok    = (float*)(ws + 65536);                       // 32 KB
    int*   tok2pos = (int*)  (ws + 131072);                      // 32 KB
    unsigned short* w2b = (unsigned short*)(ws + 1048576);       // 16 MiB
    unsigned short* Hg  = (unsigned short*)(ws + 17825792);      // 16 MiB
    unsigned short* w1b = (unsigned short*)(ws + 34603008);      // 16 MiB
    unsigned short* Og  = (unsigned short*)(ws + 34603008);      // aliases w1b

    // Ag (expert-sorted bf16 activations) lives in d_out (16 MiB); d_out is
    // rewritten by combine_kernel at the end.
    unsigned short* Ag = (unsigned short*)d_out;

    hipMemsetAsync(cnts, 0, N_EXPERT * sizeof(int), stream);
    convert_transpose_kernel<<<dim3(16, 16, 16), 256, 0, stream>>>(w1, w2, w1b, w2b);
    gate_kernel<<<dim3(N_TOKENS / 16), 256, 0, stream>>>(
        inp, gate_w, gate_b, cnts, emeta, stok);
    gather_kernel<<<dim3(N_TOKENS / 4), 256, 0, stream>>>(
        inp, cnts, emeta, Ag, tok2pos);
    ffn1_kernel<<<dim3(4096), 256, 0, stream>>>(Ag, w1b, b1, cnts, Hg);
    ffn2_kernel<<<dim3(4096), 256, 0, stream>>>(Hg, w2b, cnts, Og);
    combine_kernel<<<dim3(N_TOKENS / 4), 256, 0, stream>>>(
        Og, tok2pos, stok, emeta, b2, out);
}